// Round 3
// baseline (1478.898 us; speedup 1.0000x reference)
//
#include <hip/hip_runtime.h>
#include <hip/hip_bf16.h>
#include <math.h>

#define N_NODES 50000
#define N_EDGES 800000
#define E_TOT   (N_EDGES + N_NODES)   /* 850000, incl. self loops */
#define EMB     384
#define HID     64
#define HEADS   4
#define C1      (HEADS * HID)         /* 256 */

// ---- monotone float<->uint key for atomicMax-based float max ----
__device__ __forceinline__ unsigned fkey(float f) {
    unsigned b = __float_as_uint(f);
    return (b & 0x80000000u) ? ~b : (b | 0x80000000u);
}
__device__ __forceinline__ float funkey(unsigned u) {
    return (u & 0x80000000u) ? __uint_as_float(u ^ 0x80000000u)
                             : __uint_as_float(~u);
}

__device__ __forceinline__ void edge_sd(int e, const int* __restrict__ ei,
                                        int& s, int& d) {
    if (e < N_EDGES) { s = ei[e]; d = ei[N_EDGES + e]; }
    else             { s = d = e - N_EDGES; }
}

// ---------------- CSR build (by dst) ----------------
__global__ __launch_bounds__(256) void deg_kernel(const int* __restrict__ ei,
                                                  int* __restrict__ deg) {
    const int e = blockIdx.x * 256 + threadIdx.x;
    if (e >= E_TOT) return;
    int s, d; edge_sd(e, ei, s, d);
    atomicAdd(&deg[d], 1);
}

// single block, 1024 threads: exclusive scan of deg -> rowptr
__global__ __launch_bounds__(1024) void scan_kernel(const int* __restrict__ deg,
                                                    int* __restrict__ rowptr) {
    __shared__ int ts[1024];
    const int t  = threadIdx.x;
    const int CH = (N_NODES + 1023) / 1024;   // 49
    const int st = t * CH;
    const int en = st + CH < N_NODES ? st + CH : N_NODES;
    int s = 0;
    for (int i = st; i < en; ++i) s += deg[i];
    ts[t] = s;
    __syncthreads();
    for (int off = 1; off < 1024; off <<= 1) {
        int v = (t >= off) ? ts[t - off] : 0;
        __syncthreads();
        ts[t] += v;
        __syncthreads();
    }
    int off = ts[t] - s;                      // exclusive prefix
    for (int i = st; i < en; ++i) { rowptr[i] = off; off += deg[i]; }
}

__global__ __launch_bounds__(256) void fill_kernel(const int* __restrict__ ei,
                                                   const int* __restrict__ rowptr,
                                                   int* __restrict__ cursor,
                                                   int* __restrict__ csr) {
    const int e = blockIdx.x * 256 + threadIdx.x;
    if (e >= E_TOT) return;
    int s, d; edge_sd(e, ei, s, d);
    int p = atomicAdd(&cursor[d], 1);
    csr[rowptr[d] + p] = s;
}

// ---------------- GEMM1: X(N,384) @ W(384,256) -> H(N,256) ----------------
// As stored TRANSPOSED (As[k][n]): inner loop reads 16 node values per k as
// 4x ds_read_b128 wave-uniform broadcast instead of 16x scalar b32.
__global__ __launch_bounds__(256) void gemm1_kernel(
        const float* __restrict__ X, const float* __restrict__ W,
        float* __restrict__ H) {
    __shared__ float As[EMB][16];          // 24.6 KB
    const int n0 = blockIdx.x * 16;
    for (int i = threadIdx.x; i < 16 * EMB; i += 256) {
        int n = i / EMB, k = i % EMB;
        As[k][n] = X[(size_t)n0 * EMB + i];
    }
    __syncthreads();
    const int col = threadIdx.x;           // 0..255
    float acc[16];
#pragma unroll
    for (int n = 0; n < 16; ++n) acc[n] = 0.f;
    for (int k = 0; k < EMB; ++k) {
        const float4* ar = (const float4*)&As[k][0];
        float4 a0 = ar[0], a1 = ar[1], a2 = ar[2], a3 = ar[3];
        float w = W[k * C1 + col];
        acc[0]  = fmaf(a0.x, w, acc[0]);  acc[1]  = fmaf(a0.y, w, acc[1]);
        acc[2]  = fmaf(a0.z, w, acc[2]);  acc[3]  = fmaf(a0.w, w, acc[3]);
        acc[4]  = fmaf(a1.x, w, acc[4]);  acc[5]  = fmaf(a1.y, w, acc[5]);
        acc[6]  = fmaf(a1.z, w, acc[6]);  acc[7]  = fmaf(a1.w, w, acc[7]);
        acc[8]  = fmaf(a2.x, w, acc[8]);  acc[9]  = fmaf(a2.y, w, acc[9]);
        acc[10] = fmaf(a2.z, w, acc[10]); acc[11] = fmaf(a2.w, w, acc[11]);
        acc[12] = fmaf(a3.x, w, acc[12]); acc[13] = fmaf(a3.y, w, acc[13]);
        acc[14] = fmaf(a3.z, w, acc[14]); acc[15] = fmaf(a3.w, w, acc[15]);
    }
#pragma unroll
    for (int n = 0; n < 16; ++n) H[(size_t)(n0 + n) * C1 + col] = acc[n];
}

// -------- attention logits layer1: als/ald (N,4) --------
__global__ __launch_bounds__(256) void al1_kernel(
        const float* __restrict__ H, const float* __restrict__ as_,
        const float* __restrict__ ad_, float* __restrict__ als,
        float* __restrict__ ald) {
    const int n = blockIdx.x;
    const int h = threadIdx.x >> 6;
    const int c = threadIdx.x & 63;
    float v = H[(size_t)n * C1 + h * HID + c];
    float s = v * as_[h * HID + c];
    float d = v * ad_[h * HID + c];
#pragma unroll
    for (int off = 32; off > 0; off >>= 1) {
        s += __shfl_down(s, off);
        d += __shfl_down(d, off);
    }
    if (c == 0) { als[n * HEADS + h] = s; ald[n * HEADS + h] = d; }
}

// -------- layer2 logits: 1 head, 4 nodes per block --------
__global__ __launch_bounds__(256) void al2_kernel(
        const float* __restrict__ H, const float* __restrict__ as_,
        const float* __restrict__ ad_, float* __restrict__ als,
        float* __restrict__ ald) {
    const int n = blockIdx.x * 4 + (threadIdx.x >> 6);
    const int c = threadIdx.x & 63;
    float v = H[(size_t)n * HID + c];
    float s = v * as_[c];
    float d = v * ad_[c];
#pragma unroll
    for (int off = 32; off > 0; off >>= 1) {
        s += __shfl_down(s, off);
        d += __shfl_down(d, off);
    }
    if (c == 0) { als[n] = s; ald[n] = d; }
}

// ---- layer1 fused softmax+aggregate: block per dst, wave h = head h ----
__global__ __launch_bounds__(256) void agg1_kernel(
        const int* __restrict__ csr, const int* __restrict__ rowptr,
        const int* __restrict__ deg, const float* __restrict__ Hm,
        const float* __restrict__ als, const float* __restrict__ ald,
        float* __restrict__ xout) {
    const int d = blockIdx.x;
    const int h = threadIdx.x >> 6;
    const int c = threadIdx.x & 63;
    const int row = rowptr[d];
    const int dg  = deg[d];
    const float aldv = ald[d * HEADS + h];
    // pass 1a: segment max (lanes parallel over edges)
    float lmax = -1e30f;
    for (int j = c; j < dg; j += 64) {
        int s = csr[row + j];
        float l = als[s * HEADS + h] + aldv;
        l = l > 0.f ? l : 0.2f * l;                    // LeakyReLU(0.2)
        lmax = fmaxf(lmax, l);
    }
#pragma unroll
    for (int off = 32; off > 0; off >>= 1)
        lmax = fmaxf(lmax, __shfl_xor(lmax, off));
    // pass 1b: sum of exp
    float lsum = 0.f;
    for (int j = c; j < dg; j += 64) {
        int s = csr[row + j];
        float l = als[s * HEADS + h] + aldv;
        l = l > 0.f ? l : 0.2f * l;
        lsum += expf(l - lmax);
    }
#pragma unroll
    for (int off = 32; off > 0; off >>= 1) lsum += __shfl_xor(lsum, off);
    const float inv = 1.f / (lsum + 1e-16f);
    // pass 2: weighted gather, lane = channel, wave serial over edges
    float acc = 0.f;
    for (int j = 0; j < dg; ++j) {
        int s = csr[row + j];
        float l = als[s * HEADS + h] + aldv;
        l = l > 0.f ? l : 0.2f * l;
        float a = expf(l - lmax) * inv;
        acc = fmaf(a, Hm[(size_t)s * C1 + h * HID + c], acc);
    }
    xout[(size_t)d * C1 + h * HID + c] = acc;
}

// ---- layer2 fused softmax+aggregate: 4 dst per block, wave per dst ----
__global__ __launch_bounds__(256) void agg2_kernel(
        const int* __restrict__ csr, const int* __restrict__ rowptr,
        const int* __restrict__ deg, const float* __restrict__ Hm,
        const float* __restrict__ als, const float* __restrict__ ald,
        float* __restrict__ xout) {
    const int d = blockIdx.x * 4 + (threadIdx.x >> 6);
    const int c = threadIdx.x & 63;
    const int row = rowptr[d];
    const int dg  = deg[d];
    const float aldv = ald[d];
    float lmax = -1e30f;
    for (int j = c; j < dg; j += 64) {
        int s = csr[row + j];
        float l = als[s] + aldv;
        l = l > 0.f ? l : 0.2f * l;
        lmax = fmaxf(lmax, l);
    }
#pragma unroll
    for (int off = 32; off > 0; off >>= 1)
        lmax = fmaxf(lmax, __shfl_xor(lmax, off));
    float lsum = 0.f;
    for (int j = c; j < dg; j += 64) {
        int s = csr[row + j];
        float l = als[s] + aldv;
        l = l > 0.f ? l : 0.2f * l;
        lsum += expf(l - lmax);
    }
#pragma unroll
    for (int off = 32; off > 0; off >>= 1) lsum += __shfl_xor(lsum, off);
    const float inv = 1.f / (lsum + 1e-16f);
    float acc = 0.f;
    for (int j = 0; j < dg; ++j) {
        int s = csr[row + j];
        float l = als[s] + aldv;
        l = l > 0.f ? l : 0.2f * l;
        float a = expf(l - lmax) * inv;
        acc = fmaf(a, Hm[(size_t)s * HID + c], acc);
    }
    xout[(size_t)d * HID + c] = acc;
}

// -------- bias + ELU, in place --------
template <int CMASK>
__global__ __launch_bounds__(256) void elu_kernel(float* __restrict__ x,
                                                  const float* __restrict__ b) {
    const size_t i = (size_t)blockIdx.x * 256 + threadIdx.x;
    float v = x[i] + b[i & CMASK];
    x[i] = v > 0.f ? v : expm1f(v);
}

// ---------------- GEMM2: X(N,256) @ W(256,64) -> H(N,64) ----------------
__global__ __launch_bounds__(256) void gemm2_kernel(
        const float* __restrict__ X, const float* __restrict__ W,
        float* __restrict__ H) {
    __shared__ float Xs[16][C1];           // 16 KB
    const int n0 = blockIdx.x * 16;
    for (int i = threadIdx.x; i < 16 * C1; i += 256)
        Xs[i / C1][i % C1] = X[(size_t)n0 * C1 + i];
    __syncthreads();
    const int col = threadIdx.x & 63;
    const int g   = threadIdx.x >> 6;      // 0..3, each group does 4 nodes
    float acc[4] = {0.f, 0.f, 0.f, 0.f};
    for (int k = 0; k < C1; ++k) {
        float w = W[k * HID + col];
#pragma unroll
        for (int i = 0; i < 4; ++i) acc[i] = fmaf(Xs[g * 4 + i][k], w, acc[i]);
    }
#pragma unroll
    for (int i = 0; i < 4; ++i)
        H[(size_t)(n0 + g * 4 + i) * HID + col] = acc[i];
}

// -------- gate MLP: relu(x@gW1+gb1)@gW2+gb2 -> gate(N), track global max ----
__global__ __launch_bounds__(256) void gate_kernel(
        const float* __restrict__ x2, const float* __restrict__ gW1,
        const float* __restrict__ gb1, const float* __restrict__ gW2,
        const float* __restrict__ gb2, float* __restrict__ gate,
        unsigned* __restrict__ gmax) {
    const int n = blockIdx.x * 4 + (threadIdx.x >> 6);
    const int c = threadIdx.x & 63;
    const float* xr = x2 + (size_t)n * HID;
    float acc = 0.f;
    for (int k = 0; k < HID; ++k) acc = fmaf(xr[k], gW1[k * HID + c], acc);
    float t = acc + gb1[c];
    t = t > 0.f ? t : 0.f;
    float g = t * gW2[c];
#pragma unroll
    for (int off = 32; off > 0; off >>= 1) g += __shfl_down(g, off);
    if (c == 0) {
        float gv = g + gb2[0];
        gate[n] = gv;
        atomicMax(gmax, fkey(gv));
    }
}

// -------- exp(gate - max), block-reduced sum --------
__global__ __launch_bounds__(256) void egate_kernel(
        float* __restrict__ gate, const unsigned* __restrict__ gmax,
        float* __restrict__ gsum) {
    const int n = blockIdx.x * 256 + threadIdx.x;
    float e = 0.f;
    if (n < N_NODES) {
        float m = funkey(*gmax);
        e = expf(gate[n] - m);
        gate[n] = e;
    }
    __shared__ float red[256];
    red[threadIdx.x] = e;
    __syncthreads();
    for (int s = 128; s > 0; s >>= 1) {
        if (threadIdx.x < s) red[threadIdx.x] += red[threadIdx.x + s];
        __syncthreads();
    }
    if (threadIdx.x == 0) atomicAdd(gsum, red[0]);
}

// -------- weighted pooling: out[c] = sum_n egate[n]/gsum * x2[n,c] --------
__global__ __launch_bounds__(256) void final_kernel(
        const float* __restrict__ x2, const float* __restrict__ egate,
        const float* __restrict__ gsum, float* __restrict__ out) {
    const int c   = threadIdx.x & 63;
    const int sub = threadIdx.x >> 6;
    float acc = 0.f;
    for (int n = blockIdx.x * 4 + sub; n < N_NODES; n += gridDim.x * 4)
        acc += egate[n] * x2[(size_t)n * HID + c];
    __shared__ float red[256];
    red[threadIdx.x] = acc;
    __syncthreads();
    if (threadIdx.x < 64) {
        float t = red[threadIdx.x] + red[64 + threadIdx.x] +
                  red[128 + threadIdx.x] + red[192 + threadIdx.x];
        atomicAdd(&out[c], t / (*gsum));
    }
}

extern "C" void kernel_launch(void* const* d_in, const int* in_sizes, int n_in,
                              void* d_out, int out_size, void* d_ws, size_t ws_size,
                              hipStream_t stream) {
    const float* node_feats = (const float*)d_in[0];
    const int*   ei         = (const int*)d_in[1];
    const float* W1   = (const float*)d_in[2];
    const float* as1  = (const float*)d_in[3];
    const float* ad1  = (const float*)d_in[4];
    const float* b1   = (const float*)d_in[5];
    const float* W2   = (const float*)d_in[6];
    const float* as2  = (const float*)d_in[7];
    const float* ad2  = (const float*)d_in[8];
    const float* b2   = (const float*)d_in[9];
    const float* gW1  = (const float*)d_in[10];
    const float* gb1  = (const float*)d_in[11];
    const float* gW2  = (const float*)d_in[12];
    const float* gb2  = (const float*)d_in[13];
    float* out = (float*)d_out;

    // ---- workspace layout (4-byte units) ----
    float* f = (float*)d_ws;
    size_t o = 0;
    float* h1   = f + o; o += (size_t)N_NODES * C1;     // 12.8M
    float* h2   = f + o; o += (size_t)N_NODES * HID;    // 3.2M
    float* x1   = f + o; o += (size_t)N_NODES * C1;     // 12.8M
    float* x2   = f + o; o += (size_t)N_NODES * HID;    // 3.2M
    float* als1 = f + o; o += (size_t)N_NODES * HEADS;
    float* ald1 = f + o; o += (size_t)N_NODES * HEADS;
    float* als2 = f + o; o += N_NODES;
    float* ald2 = f + o; o += N_NODES;
    float* gate = f + o; o += N_NODES;
    int* csr    = (int*)(f + o); o += E_TOT;            // 850K
    int* rowptr = (int*)(f + o); o += N_NODES;
    // ---- contiguous zero region ----
    float* zero0 = f + o;
    int* deg    = (int*)(f + o); o += N_NODES;
    int* cursor = (int*)(f + o); o += N_NODES;
    float* scal = f + o; o += 2;  // [0]=gmax key (uint), [1]=gsum
    size_t zbytes = (size_t)((f + o) - zero0) * sizeof(float);

    hipMemsetAsync(zero0, 0, zbytes, stream);
    hipMemsetAsync(out, 0, (size_t)out_size * sizeof(float), stream);

    const int EB = (E_TOT + 255) / 256;           // 3321

    // ----- CSR build (shared by both layers) -----
    deg_kernel<<<EB, 256, 0, stream>>>(ei, deg);
    scan_kernel<<<1, 1024, 0, stream>>>(deg, rowptr);
    fill_kernel<<<EB, 256, 0, stream>>>(ei, rowptr, cursor, csr);

    // ----- layer 1 -----
    gemm1_kernel<<<N_NODES / 16, 256, 0, stream>>>(node_feats, W1, h1);
    al1_kernel<<<N_NODES, 256, 0, stream>>>(h1, as1, ad1, als1, ald1);
    agg1_kernel<<<N_NODES, 256, 0, stream>>>(csr, rowptr, deg, h1, als1, ald1, x1);
    elu_kernel<255><<<(N_NODES * C1) / 256, 256, 0, stream>>>(x1, b1);

    // ----- layer 2 -----
    gemm2_kernel<<<N_NODES / 16, 256, 0, stream>>>(x1, W2, h2);
    al2_kernel<<<N_NODES / 4, 256, 0, stream>>>(h2, as2, ad2, als2, ald2);
    agg2_kernel<<<N_NODES / 4, 256, 0, stream>>>(csr, rowptr, deg, h2, als2, ald2, x2);
    elu_kernel<63><<<(N_NODES * HID) / 256, 256, 0, stream>>>(x2, b2);

    // ----- attentional pooling -----
    gate_kernel<<<N_NODES / 4, 256, 0, stream>>>(x2, gW1, gb1, gW2, gb2,
                                                 gate, (unsigned*)&scal[0]);
    egate_kernel<<<(N_NODES + 255) / 256, 256, 0, stream>>>(
        gate, (const unsigned*)&scal[0], &scal[1]);
    final_kernel<<<256, 256, 0, stream>>>(x2, gate, &scal[1], out);
}

// Round 4
// 948.537 us; speedup vs baseline: 1.5591x; 1.5591x over previous
//
#include <hip/hip_runtime.h>
#include <hip/hip_bf16.h>
#include <math.h>

#define N_NODES 50000
#define N_EDGES 800000
#define E_TOT   (N_EDGES + N_NODES)   /* 850000, incl. self loops */
#define EMB     384
#define HID     64
#define HEADS   4
#define C1      (HEADS * HID)         /* 256 */

// ---- monotone float<->uint key for atomicMax-based float max ----
// key(finite x) > 0 for all x, so memset(0) is a valid identity for max.
__device__ __forceinline__ unsigned fkey(float f) {
    unsigned b = __float_as_uint(f);
    return (b & 0x80000000u) ? ~b : (b | 0x80000000u);
}
__device__ __forceinline__ float funkey(unsigned u) {
    return (u & 0x80000000u) ? __uint_as_float(u ^ 0x80000000u)
                             : __uint_as_float(~u);
}

__device__ __forceinline__ void edge_sd(int e, const int* __restrict__ ei,
                                        int& s, int& d) {
    if (e < N_EDGES) { s = ei[e]; d = ei[N_EDGES + e]; }
    else             { s = d = e - N_EDGES; }
}

// ---------------- CSR build (by dst) ----------------
__global__ __launch_bounds__(256) void deg_kernel(const int* __restrict__ ei,
                                                  int* __restrict__ deg) {
    const int e = blockIdx.x * 256 + threadIdx.x;
    if (e >= E_TOT) return;
    int s, d; edge_sd(e, ei, s, d);
    atomicAdd(&deg[d], 1);
}

// single block, 1024 threads: exclusive scan of deg -> rowptr
__global__ __launch_bounds__(1024) void scan_kernel(const int* __restrict__ deg,
                                                    int* __restrict__ rowptr) {
    __shared__ int ts[1024];
    const int t  = threadIdx.x;
    const int CH = (N_NODES + 1023) / 1024;   // 49
    const int st = t * CH;
    const int en = st + CH < N_NODES ? st + CH : N_NODES;
    int s = 0;
    for (int i = st; i < en; ++i) s += deg[i];
    ts[t] = s;
    __syncthreads();
    for (int off = 1; off < 1024; off <<= 1) {
        int v = (t >= off) ? ts[t - off] : 0;
        __syncthreads();
        ts[t] += v;
        __syncthreads();
    }
    int off = ts[t] - s;                      // exclusive prefix
    for (int i = st; i < en; ++i) { rowptr[i] = off; off += deg[i]; }
}

__global__ __launch_bounds__(256) void fill_kernel(const int* __restrict__ ei,
                                                   const int* __restrict__ rowptr,
                                                   int* __restrict__ cursor,
                                                   int* __restrict__ csr) {
    const int e = blockIdx.x * 256 + threadIdx.x;
    if (e >= E_TOT) return;
    int s, d; edge_sd(e, ei, s, d);
    int p = atomicAdd(&cursor[d], 1);
    csr[rowptr[d] + p] = s;
}

// ---------------- GEMM1: X(N,384) @ W(384,256) -> H(N,256) ----------------
// As stored TRANSPOSED (As[k][n]): inner loop reads 16 node values per k as
// 4x ds_read_b128 wave-uniform broadcast instead of 16x scalar b32.
__global__ __launch_bounds__(256) void gemm1_kernel(
        const float* __restrict__ X, const float* __restrict__ W,
        float* __restrict__ H) {
    __shared__ float As[EMB][16];          // 24.6 KB
    const int n0 = blockIdx.x * 16;
    for (int i = threadIdx.x; i < 16 * EMB; i += 256) {
        int n = i / EMB, k = i % EMB;
        As[k][n] = X[(size_t)n0 * EMB + i];
    }
    __syncthreads();
    const int col = threadIdx.x;           // 0..255
    float acc[16];
#pragma unroll
    for (int n = 0; n < 16; ++n) acc[n] = 0.f;
    for (int k = 0; k < EMB; ++k) {
        const float4* ar = (const float4*)&As[k][0];
        float4 a0 = ar[0], a1 = ar[1], a2 = ar[2], a3 = ar[3];
        float w = W[k * C1 + col];
        acc[0]  = fmaf(a0.x, w, acc[0]);  acc[1]  = fmaf(a0.y, w, acc[1]);
        acc[2]  = fmaf(a0.z, w, acc[2]);  acc[3]  = fmaf(a0.w, w, acc[3]);
        acc[4]  = fmaf(a1.x, w, acc[4]);  acc[5]  = fmaf(a1.y, w, acc[5]);
        acc[6]  = fmaf(a1.z, w, acc[6]);  acc[7]  = fmaf(a1.w, w, acc[7]);
        acc[8]  = fmaf(a2.x, w, acc[8]);  acc[9]  = fmaf(a2.y, w, acc[9]);
        acc[10] = fmaf(a2.z, w, acc[10]); acc[11] = fmaf(a2.w, w, acc[11]);
        acc[12] = fmaf(a3.x, w, acc[12]); acc[13] = fmaf(a3.y, w, acc[13]);
        acc[14] = fmaf(a3.z, w, acc[14]); acc[15] = fmaf(a3.w, w, acc[15]);
    }
#pragma unroll
    for (int n = 0; n < 16; ++n) H[(size_t)(n0 + n) * C1 + col] = acc[n];
}

// -------- attention logits layer1: als/ald (N,4) --------
__global__ __launch_bounds__(256) void al1_kernel(
        const float* __restrict__ H, const float* __restrict__ as_,
        const float* __restrict__ ad_, float* __restrict__ als,
        float* __restrict__ ald) {
    const int n = blockIdx.x;
    const int h = threadIdx.x >> 6;
    const int c = threadIdx.x & 63;
    float v = H[(size_t)n * C1 + h * HID + c];
    float s = v * as_[h * HID + c];
    float d = v * ad_[h * HID + c];
#pragma unroll
    for (int off = 32; off > 0; off >>= 1) {
        s += __shfl_down(s, off);
        d += __shfl_down(d, off);
    }
    if (c == 0) { als[n * HEADS + h] = s; ald[n * HEADS + h] = d; }
}

// -------- layer2 logits: 1 head, 4 nodes per block --------
__global__ __launch_bounds__(256) void al2_kernel(
        const float* __restrict__ H, const float* __restrict__ as_,
        const float* __restrict__ ad_, float* __restrict__ als,
        float* __restrict__ ald) {
    const int n = blockIdx.x * 4 + (threadIdx.x >> 6);
    const int c = threadIdx.x & 63;
    float v = H[(size_t)n * HID + c];
    float s = v * as_[c];
    float d = v * ad_[c];
#pragma unroll
    for (int off = 32; off > 0; off >>= 1) {
        s += __shfl_down(s, off);
        d += __shfl_down(d, off);
    }
    if (c == 0) { als[n] = s; ald[n] = d; }
}

// ---- layer1 fused softmax+aggregate: block per dst, wave h = head h ----
__global__ __launch_bounds__(256) void agg1_kernel(
        const int* __restrict__ csr, const int* __restrict__ rowptr,
        const int* __restrict__ deg, const float* __restrict__ Hm,
        const float* __restrict__ als, const float* __restrict__ ald,
        float* __restrict__ xout) {
    const int d = blockIdx.x;
    const int h = threadIdx.x >> 6;
    const int c = threadIdx.x & 63;
    const int row = rowptr[d];
    const int dg  = deg[d];
    const float aldv = ald[d * HEADS + h];
    // pass 1a: segment max (lanes parallel over edges)
    float lmax = -1e30f;
    for (int j = c; j < dg; j += 64) {
        int s = csr[row + j];
        float l = als[s * HEADS + h] + aldv;
        l = l > 0.f ? l : 0.2f * l;                    // LeakyReLU(0.2)
        lmax = fmaxf(lmax, l);
    }
#pragma unroll
    for (int off = 32; off > 0; off >>= 1)
        lmax = fmaxf(lmax, __shfl_xor(lmax, off));
    // pass 1b: sum of exp
    float lsum = 0.f;
    for (int j = c; j < dg; j += 64) {
        int s = csr[row + j];
        float l = als[s * HEADS + h] + aldv;
        l = l > 0.f ? l : 0.2f * l;
        lsum += expf(l - lmax);
    }
#pragma unroll
    for (int off = 32; off > 0; off >>= 1) lsum += __shfl_xor(lsum, off);
    const float inv = 1.f / (lsum + 1e-16f);
    // pass 2: weighted gather, lane = channel, wave serial over edges
    float acc = 0.f;
    for (int j = 0; j < dg; ++j) {
        int s = csr[row + j];
        float l = als[s * HEADS + h] + aldv;
        l = l > 0.f ? l : 0.2f * l;
        float a = expf(l - lmax) * inv;
        acc = fmaf(a, Hm[(size_t)s * C1 + h * HID + c], acc);
    }
    xout[(size_t)d * C1 + h * HID + c] = acc;
}

// ---- layer2 fused softmax+aggregate: 4 dst per block, wave per dst ----
__global__ __launch_bounds__(256) void agg2_kernel(
        const int* __restrict__ csr, const int* __restrict__ rowptr,
        const int* __restrict__ deg, const float* __restrict__ Hm,
        const float* __restrict__ als, const float* __restrict__ ald,
        float* __restrict__ xout) {
    const int d = blockIdx.x * 4 + (threadIdx.x >> 6);
    const int c = threadIdx.x & 63;
    const int row = rowptr[d];
    const int dg  = deg[d];
    const float aldv = ald[d];
    float lmax = -1e30f;
    for (int j = c; j < dg; j += 64) {
        int s = csr[row + j];
        float l = als[s] + aldv;
        l = l > 0.f ? l : 0.2f * l;
        lmax = fmaxf(lmax, l);
    }
#pragma unroll
    for (int off = 32; off > 0; off >>= 1)
        lmax = fmaxf(lmax, __shfl_xor(lmax, off));
    float lsum = 0.f;
    for (int j = c; j < dg; j += 64) {
        int s = csr[row + j];
        float l = als[s] + aldv;
        l = l > 0.f ? l : 0.2f * l;
        lsum += expf(l - lmax);
    }
#pragma unroll
    for (int off = 32; off > 0; off >>= 1) lsum += __shfl_xor(lsum, off);
    const float inv = 1.f / (lsum + 1e-16f);
    float acc = 0.f;
    for (int j = 0; j < dg; ++j) {
        int s = csr[row + j];
        float l = als[s] + aldv;
        l = l > 0.f ? l : 0.2f * l;
        float a = expf(l - lmax) * inv;
        acc = fmaf(a, Hm[(size_t)s * HID + c], acc);
    }
    xout[(size_t)d * HID + c] = acc;
}

// -------- bias + ELU, in place --------
template <int CMASK>
__global__ __launch_bounds__(256) void elu_kernel(float* __restrict__ x,
                                                  const float* __restrict__ b) {
    const size_t i = (size_t)blockIdx.x * 256 + threadIdx.x;
    float v = x[i] + b[i & CMASK];
    x[i] = v > 0.f ? v : expm1f(v);
}

// ---------------- GEMM2: X(N,256) @ W(256,64) -> H(N,64) ----------------
__global__ __launch_bounds__(256) void gemm2_kernel(
        const float* __restrict__ X, const float* __restrict__ W,
        float* __restrict__ H) {
    __shared__ float Xs[16][C1];           // 16 KB
    const int n0 = blockIdx.x * 16;
    for (int i = threadIdx.x; i < 16 * C1; i += 256)
        Xs[i / C1][i % C1] = X[(size_t)n0 * C1 + i];
    __syncthreads();
    const int col = threadIdx.x & 63;
    const int g   = threadIdx.x >> 6;      // 0..3, each group does 4 nodes
    float acc[4] = {0.f, 0.f, 0.f, 0.f};
    for (int k = 0; k < C1; ++k) {
        float w = W[k * HID + col];
#pragma unroll
        for (int i = 0; i < 4; ++i) acc[i] = fmaf(Xs[g * 4 + i][k], w, acc[i]);
    }
#pragma unroll
    for (int i = 0; i < 4; ++i)
        H[(size_t)(n0 + g * 4 + i) * HID + col] = acc[i];
}

// -------- gate MLP: relu(x@gW1+gb1)@gW2+gb2 -> gate(N); NO global atomic ----
__global__ __launch_bounds__(256) void gate_kernel(
        const float* __restrict__ x2, const float* __restrict__ gW1,
        const float* __restrict__ gb1, const float* __restrict__ gW2,
        const float* __restrict__ gb2, float* __restrict__ gate) {
    const int n = blockIdx.x * 4 + (threadIdx.x >> 6);
    const int c = threadIdx.x & 63;
    const float* xr = x2 + (size_t)n * HID;
    float acc = 0.f;
    for (int k = 0; k < HID; ++k) acc = fmaf(xr[k], gW1[k * HID + c], acc);
    float t = acc + gb1[c];
    t = t > 0.f ? t : 0.f;
    float g = t * gW2[c];
#pragma unroll
    for (int off = 32; off > 0; off >>= 1) g += __shfl_down(g, off);
    if (c == 0) gate[n] = g + gb2[0];
}

// -------- hierarchical global max of gate: 48 blocks -> 48 atomics --------
__global__ __launch_bounds__(256) void gmax_kernel(
        const float* __restrict__ gate, unsigned* __restrict__ gmax) {
    float m = -1e30f;
    for (int n = blockIdx.x * 256 + threadIdx.x; n < N_NODES;
         n += gridDim.x * 256)
        m = fmaxf(m, gate[n]);
    __shared__ float red[256];
    red[threadIdx.x] = m;
    __syncthreads();
    for (int s = 128; s > 0; s >>= 1) {
        if (threadIdx.x < s)
            red[threadIdx.x] = fmaxf(red[threadIdx.x], red[threadIdx.x + s]);
        __syncthreads();
    }
    if (threadIdx.x == 0) atomicMax(gmax, fkey(red[0]));
}

// -------- exp(gate - max), block-reduced sum --------
__global__ __launch_bounds__(256) void egate_kernel(
        float* __restrict__ gate, const unsigned* __restrict__ gmax,
        float* __restrict__ gsum) {
    const int n = blockIdx.x * 256 + threadIdx.x;
    float e = 0.f;
    if (n < N_NODES) {
        float m = funkey(*gmax);
        e = expf(gate[n] - m);
        gate[n] = e;
    }
    __shared__ float red[256];
    red[threadIdx.x] = e;
    __syncthreads();
    for (int s = 128; s > 0; s >>= 1) {
        if (threadIdx.x < s) red[threadIdx.x] += red[threadIdx.x + s];
        __syncthreads();
    }
    if (threadIdx.x == 0) atomicAdd(gsum, red[0]);
}

// -------- weighted pooling: out[c] = sum_n egate[n]/gsum * x2[n,c] --------
__global__ __launch_bounds__(256) void final_kernel(
        const float* __restrict__ x2, const float* __restrict__ egate,
        const float* __restrict__ gsum, float* __restrict__ out) {
    const int c   = threadIdx.x & 63;
    const int sub = threadIdx.x >> 6;
    float acc = 0.f;
    for (int n = blockIdx.x * 4 + sub; n < N_NODES; n += gridDim.x * 4)
        acc += egate[n] * x2[(size_t)n * HID + c];
    __shared__ float red[256];
    red[threadIdx.x] = acc;
    __syncthreads();
    if (threadIdx.x < 64) {
        float t = red[threadIdx.x] + red[64 + threadIdx.x] +
                  red[128 + threadIdx.x] + red[192 + threadIdx.x];
        atomicAdd(&out[c], t / (*gsum));
    }
}

extern "C" void kernel_launch(void* const* d_in, const int* in_sizes, int n_in,
                              void* d_out, int out_size, void* d_ws, size_t ws_size,
                              hipStream_t stream) {
    const float* node_feats = (const float*)d_in[0];
    const int*   ei         = (const int*)d_in[1];
    const float* W1   = (const float*)d_in[2];
    const float* as1  = (const float*)d_in[3];
    const float* ad1  = (const float*)d_in[4];
    const float* b1   = (const float*)d_in[5];
    const float* W2   = (const float*)d_in[6];
    const float* as2  = (const float*)d_in[7];
    const float* ad2  = (const float*)d_in[8];
    const float* b2   = (const float*)d_in[9];
    const float* gW1  = (const float*)d_in[10];
    const float* gb1  = (const float*)d_in[11];
    const float* gW2  = (const float*)d_in[12];
    const float* gb2  = (const float*)d_in[13];
    float* out = (float*)d_out;

    // ---- workspace layout (4-byte units) ----
    float* f = (float*)d_ws;
    size_t o = 0;
    float* h1   = f + o; o += (size_t)N_NODES * C1;     // 12.8M
    float* h2   = f + o; o += (size_t)N_NODES * HID;    // 3.2M
    float* x1   = f + o; o += (size_t)N_NODES * C1;     // 12.8M
    float* x2   = f + o; o += (size_t)N_NODES * HID;    // 3.2M
    float* als1 = f + o; o += (size_t)N_NODES * HEADS;
    float* ald1 = f + o; o += (size_t)N_NODES * HEADS;
    float* als2 = f + o; o += N_NODES;
    float* ald2 = f + o; o += N_NODES;
    float* gate = f + o; o += N_NODES;
    int* csr    = (int*)(f + o); o += E_TOT;            // 850K
    int* rowptr = (int*)(f + o); o += N_NODES;
    // ---- contiguous zero region ----
    float* zero0 = f + o;
    int* deg    = (int*)(f + o); o += N_NODES;
    int* cursor = (int*)(f + o); o += N_NODES;
    float* scal = f + o; o += 2;  // [0]=gmax key (uint), [1]=gsum
    size_t zbytes = (size_t)((f + o) - zero0) * sizeof(float);

    hipMemsetAsync(zero0, 0, zbytes, stream);
    hipMemsetAsync(out, 0, (size_t)out_size * sizeof(float), stream);

    const int EB = (E_TOT + 255) / 256;           // 3321

    // ----- CSR build (shared by both layers) -----
    deg_kernel<<<EB, 256, 0, stream>>>(ei, deg);
    scan_kernel<<<1, 1024, 0, stream>>>(deg, rowptr);
    fill_kernel<<<EB, 256, 0, stream>>>(ei, rowptr, cursor, csr);

    // ----- layer 1 -----
    gemm1_kernel<<<N_NODES / 16, 256, 0, stream>>>(node_feats, W1, h1);
    al1_kernel<<<N_NODES, 256, 0, stream>>>(h1, as1, ad1, als1, ald1);
    agg1_kernel<<<N_NODES, 256, 0, stream>>>(csr, rowptr, deg, h1, als1, ald1, x1);
    elu_kernel<255><<<(N_NODES * C1) / 256, 256, 0, stream>>>(x1, b1);

    // ----- layer 2 -----
    gemm2_kernel<<<N_NODES / 16, 256, 0, stream>>>(x1, W2, h2);
    al2_kernel<<<N_NODES / 4, 256, 0, stream>>>(h2, as2, ad2, als2, ald2);
    agg2_kernel<<<N_NODES / 4, 256, 0, stream>>>(csr, rowptr, deg, h2, als2, ald2, x2);
    elu_kernel<63><<<(N_NODES * HID) / 256, 256, 0, stream>>>(x2, b2);

    // ----- attentional pooling -----
    gate_kernel<<<N_NODES / 4, 256, 0, stream>>>(x2, gW1, gb1, gW2, gb2, gate);
    gmax_kernel<<<48, 256, 0, stream>>>(gate, (unsigned*)&scal[0]);
    egate_kernel<<<(N_NODES + 255) / 256, 256, 0, stream>>>(
        gate, (const unsigned*)&scal[0], &scal[1]);
    final_kernel<<<256, 256, 0, stream>>>(x2, gate, &scal[1], out);
}

// Round 5
// 867.203 us; speedup vs baseline: 1.7054x; 1.0938x over previous
//
#include <hip/hip_runtime.h>
#include <hip/hip_bf16.h>
#include <math.h>

#define N_NODES 50000
#define N_EDGES 800000
#define E_TOT   (N_EDGES + N_NODES)   /* 850000, incl. self loops */
#define EMB     384
#define HID     64
#define HEADS   4
#define C1      (HEADS * HID)         /* 256 */
#define CHUNK   256                   /* edges staged per LDS chunk */

// ---- monotone float<->uint key for atomicMax-based float max ----
// key(finite x) > 0 for all x, so memset(0) is a valid identity for max.
__device__ __forceinline__ unsigned fkey(float f) {
    unsigned b = __float_as_uint(f);
    return (b & 0x80000000u) ? ~b : (b | 0x80000000u);
}
__device__ __forceinline__ float funkey(unsigned u) {
    return (u & 0x80000000u) ? __uint_as_float(u ^ 0x80000000u)
                             : __uint_as_float(~u);
}

__device__ __forceinline__ void edge_sd(int e, const int* __restrict__ ei,
                                        int& s, int& d) {
    if (e < N_EDGES) { s = ei[e]; d = ei[N_EDGES + e]; }
    else             { s = d = e - N_EDGES; }
}

// ---------------- CSR build (by dst) ----------------
__global__ __launch_bounds__(256) void deg_kernel(const int* __restrict__ ei,
                                                  int* __restrict__ deg) {
    const int e = blockIdx.x * 256 + threadIdx.x;
    if (e >= E_TOT) return;
    int s, d; edge_sd(e, ei, s, d);
    atomicAdd(&deg[d], 1);
}

// single block, 1024 threads: exclusive scan of deg -> rowptr
__global__ __launch_bounds__(1024) void scan_kernel(const int* __restrict__ deg,
                                                    int* __restrict__ rowptr) {
    __shared__ int ts[1024];
    const int t  = threadIdx.x;
    const int CH = (N_NODES + 1023) / 1024;   // 49
    const int st = t * CH;
    const int en = st + CH < N_NODES ? st + CH : N_NODES;
    int s = 0;
    for (int i = st; i < en; ++i) s += deg[i];
    ts[t] = s;
    __syncthreads();
    for (int off = 1; off < 1024; off <<= 1) {
        int v = (t >= off) ? ts[t - off] : 0;
        __syncthreads();
        ts[t] += v;
        __syncthreads();
    }
    int off = ts[t] - s;                      // exclusive prefix
    for (int i = st; i < en; ++i) { rowptr[i] = off; off += deg[i]; }
}

__global__ __launch_bounds__(256) void fill_kernel(const int* __restrict__ ei,
                                                   const int* __restrict__ rowptr,
                                                   int* __restrict__ cursor,
                                                   int* __restrict__ csr) {
    const int e = blockIdx.x * 256 + threadIdx.x;
    if (e >= E_TOT) return;
    int s, d; edge_sd(e, ei, s, d);
    int p = atomicAdd(&cursor[d], 1);
    csr[rowptr[d] + p] = s;
}

// ---------------- GEMM1: X(N,384) @ W(384,256) -> H(N,256) ----------------
__global__ __launch_bounds__(256) void gemm1_kernel(
        const float* __restrict__ X, const float* __restrict__ W,
        float* __restrict__ H) {
    __shared__ float As[EMB][16];          // 24.6 KB
    const int n0 = blockIdx.x * 16;
    for (int i = threadIdx.x; i < 16 * EMB; i += 256) {
        int n = i / EMB, k = i % EMB;
        As[k][n] = X[(size_t)n0 * EMB + i];
    }
    __syncthreads();
    const int col = threadIdx.x;           // 0..255
    float acc[16];
#pragma unroll
    for (int n = 0; n < 16; ++n) acc[n] = 0.f;
    for (int k = 0; k < EMB; ++k) {
        const float4* ar = (const float4*)&As[k][0];
        float4 a0 = ar[0], a1 = ar[1], a2 = ar[2], a3 = ar[3];
        float w = W[k * C1 + col];
        acc[0]  = fmaf(a0.x, w, acc[0]);  acc[1]  = fmaf(a0.y, w, acc[1]);
        acc[2]  = fmaf(a0.z, w, acc[2]);  acc[3]  = fmaf(a0.w, w, acc[3]);
        acc[4]  = fmaf(a1.x, w, acc[4]);  acc[5]  = fmaf(a1.y, w, acc[5]);
        acc[6]  = fmaf(a1.z, w, acc[6]);  acc[7]  = fmaf(a1.w, w, acc[7]);
        acc[8]  = fmaf(a2.x, w, acc[8]);  acc[9]  = fmaf(a2.y, w, acc[9]);
        acc[10] = fmaf(a2.z, w, acc[10]); acc[11] = fmaf(a2.w, w, acc[11]);
        acc[12] = fmaf(a3.x, w, acc[12]); acc[13] = fmaf(a3.y, w, acc[13]);
        acc[14] = fmaf(a3.z, w, acc[14]); acc[15] = fmaf(a3.w, w, acc[15]);
    }
#pragma unroll
    for (int n = 0; n < 16; ++n) H[(size_t)(n0 + n) * C1 + col] = acc[n];
}

// -------- attention logits layer1: als/ald (N,4) --------
__global__ __launch_bounds__(256) void al1_kernel(
        const float* __restrict__ H, const float* __restrict__ as_,
        const float* __restrict__ ad_, float* __restrict__ als,
        float* __restrict__ ald) {
    const int n = blockIdx.x;
    const int h = threadIdx.x >> 6;
    const int c = threadIdx.x & 63;
    float v = H[(size_t)n * C1 + h * HID + c];
    float s = v * as_[h * HID + c];
    float d = v * ad_[h * HID + c];
#pragma unroll
    for (int off = 32; off > 0; off >>= 1) {
        s += __shfl_down(s, off);
        d += __shfl_down(d, off);
    }
    if (c == 0) { als[n * HEADS + h] = s; ald[n * HEADS + h] = d; }
}

// -------- layer2 logits: 1 head, 4 nodes per block --------
__global__ __launch_bounds__(256) void al2_kernel(
        const float* __restrict__ H, const float* __restrict__ as_,
        const float* __restrict__ ad_, float* __restrict__ als,
        float* __restrict__ ald) {
    const int n = blockIdx.x * 4 + (threadIdx.x >> 6);
    const int c = threadIdx.x & 63;
    float v = H[(size_t)n * HID + c];
    float s = v * as_[c];
    float d = v * ad_[c];
#pragma unroll
    for (int off = 32; off > 0; off >>= 1) {
        s += __shfl_down(s, off);
        d += __shfl_down(d, off);
    }
    if (c == 0) { als[n] = s; ald[n] = d; }
}

// ---- layer1 fused softmax+aggregate: block per dst ----
// Phase A: per-head lmax/lsum (wave h = head h), alphas staged in LDS.
// Phase B: whole-row float4 gather; 4 waves interleave edges; LDS reduce.
__global__ __launch_bounds__(256) void agg1_kernel(
        const int* __restrict__ csr, const int* __restrict__ rowptr,
        const int* __restrict__ deg, const float* __restrict__ Hm,
        const float* __restrict__ als, const float* __restrict__ ald,
        float* __restrict__ xout) {
    __shared__ float alpha_s[CHUNK][5];    // pad->stride 5: conflict-free writes
    __shared__ int   src_s[CHUNK];
    __shared__ float red_s[4][C1];
    const int d = blockIdx.x;
    const int w = threadIdx.x >> 6;        // wave id == head for phase A
    const int c = threadIdx.x & 63;
    const int row = rowptr[d];
    const int dg  = deg[d];
    const float aldv = ald[d * HEADS + w];
    // phase A1: per-head segment max (lanes parallel over edges)
    float lmax = -1e30f;
    for (int j = c; j < dg; j += 64) {
        int s = csr[row + j];
        float l = als[s * HEADS + w] + aldv;
        l = l > 0.f ? l : 0.2f * l;                    // LeakyReLU(0.2)
        lmax = fmaxf(lmax, l);
    }
#pragma unroll
    for (int off = 32; off > 0; off >>= 1)
        lmax = fmaxf(lmax, __shfl_xor(lmax, off));
    // phase A2: sum of exp
    float lsum = 0.f;
    for (int j = c; j < dg; j += 64) {
        int s = csr[row + j];
        float l = als[s * HEADS + w] + aldv;
        l = l > 0.f ? l : 0.2f * l;
        lsum += expf(l - lmax);
    }
#pragma unroll
    for (int off = 32; off > 0; off >>= 1) lsum += __shfl_xor(lsum, off);
    const float inv = 1.f / (lsum + 1e-16f);

    // phase B: gather. Lane c holds channels 4c..4c+3 (head = c>>4).
    float4 acc = make_float4(0.f, 0.f, 0.f, 0.f);
    const int myh = c >> 4;
    for (int base = 0; base < dg; base += CHUNK) {
        const int cn = (dg - base) < CHUNK ? (dg - base) : CHUNK;
        // stage: wave w computes alpha for head w; wave 0 also stages src
        for (int j = c; j < cn; j += 64) {
            int s = csr[row + base + j];
            if (w == 0) src_s[j] = s;
            float l = als[s * HEADS + w] + aldv;
            l = l > 0.f ? l : 0.2f * l;
            alpha_s[j][w] = expf(l - lmax) * inv;
        }
        __syncthreads();
        for (int j = w; j < cn; j += 4) {
            int s = src_s[j];
            float a = alpha_s[j][myh];
            const float4 v = *(const float4*)&Hm[(size_t)s * C1 + c * 4];
            acc.x = fmaf(a, v.x, acc.x);
            acc.y = fmaf(a, v.y, acc.y);
            acc.z = fmaf(a, v.z, acc.z);
            acc.w = fmaf(a, v.w, acc.w);
        }
        __syncthreads();
    }
    *(float4*)&red_s[w][c * 4] = acc;
    __syncthreads();
    float r = red_s[0][threadIdx.x] + red_s[1][threadIdx.x] +
              red_s[2][threadIdx.x] + red_s[3][threadIdx.x];
    xout[(size_t)d * C1 + threadIdx.x] = r;
}

// ---- layer2 fused softmax+aggregate: block per dst, 1 head ----
__global__ __launch_bounds__(256) void agg2_kernel(
        const int* __restrict__ csr, const int* __restrict__ rowptr,
        const int* __restrict__ deg, const float* __restrict__ Hm,
        const float* __restrict__ als, const float* __restrict__ ald,
        float* __restrict__ xout) {
    __shared__ float alpha_s[CHUNK];
    __shared__ int   src_s[CHUNK];
    __shared__ float red_s[4][HID];
    const int d = blockIdx.x;
    const int w = threadIdx.x >> 6;
    const int c = threadIdx.x & 63;
    const int row = rowptr[d];
    const int dg  = deg[d];
    const float aldv = ald[d];
    // all 4 waves redundantly compute lmax/lsum (cheap; avoids extra barriers)
    float lmax = -1e30f;
    for (int j = c; j < dg; j += 64) {
        int s = csr[row + j];
        float l = als[s] + aldv;
        l = l > 0.f ? l : 0.2f * l;
        lmax = fmaxf(lmax, l);
    }
#pragma unroll
    for (int off = 32; off > 0; off >>= 1)
        lmax = fmaxf(lmax, __shfl_xor(lmax, off));
    float lsum = 0.f;
    for (int j = c; j < dg; j += 64) {
        int s = csr[row + j];
        float l = als[s] + aldv;
        l = l > 0.f ? l : 0.2f * l;
        lsum += expf(l - lmax);
    }
#pragma unroll
    for (int off = 32; off > 0; off >>= 1) lsum += __shfl_xor(lsum, off);
    const float inv = 1.f / (lsum + 1e-16f);

    float acc = 0.f;
    for (int base = 0; base < dg; base += CHUNK) {
        const int cn = (dg - base) < CHUNK ? (dg - base) : CHUNK;
        for (int j = threadIdx.x; j < cn; j += 256) {
            int s = csr[row + base + j];
            src_s[j] = s;
            float l = als[s] + aldv;
            l = l > 0.f ? l : 0.2f * l;
            alpha_s[j] = expf(l - lmax) * inv;
        }
        __syncthreads();
        for (int j = w; j < cn; j += 4)
            acc = fmaf(alpha_s[j], Hm[(size_t)src_s[j] * HID + c], acc);
        __syncthreads();
    }
    red_s[w][c] = acc;
    __syncthreads();
    if (threadIdx.x < HID) {
        float r = red_s[0][threadIdx.x] + red_s[1][threadIdx.x] +
                  red_s[2][threadIdx.x] + red_s[3][threadIdx.x];
        xout[(size_t)d * HID + threadIdx.x] = r;
    }
}

// -------- bias + ELU, in place --------
template <int CMASK>
__global__ __launch_bounds__(256) void elu_kernel(float* __restrict__ x,
                                                  const float* __restrict__ b) {
    const size_t i = (size_t)blockIdx.x * 256 + threadIdx.x;
    float v = x[i] + b[i & CMASK];
    x[i] = v > 0.f ? v : expm1f(v);
}

// ---------------- GEMM2: X(N,256) @ W(256,64) -> H(N,64) ----------------
__global__ __launch_bounds__(256) void gemm2_kernel(
        const float* __restrict__ X, const float* __restrict__ W,
        float* __restrict__ H) {
    __shared__ float Xs[16][C1];           // 16 KB
    const int n0 = blockIdx.x * 16;
    for (int i = threadIdx.x; i < 16 * C1; i += 256)
        Xs[i / C1][i % C1] = X[(size_t)n0 * C1 + i];
    __syncthreads();
    const int col = threadIdx.x & 63;
    const int g   = threadIdx.x >> 6;      // 0..3, each group does 4 nodes
    float acc[4] = {0.f, 0.f, 0.f, 0.f};
    for (int k = 0; k < C1; ++k) {
        float w = W[k * HID + col];
#pragma unroll
        for (int i = 0; i < 4; ++i) acc[i] = fmaf(Xs[g * 4 + i][k], w, acc[i]);
    }
#pragma unroll
    for (int i = 0; i < 4; ++i)
        H[(size_t)(n0 + g * 4 + i) * HID + col] = acc[i];
}

// -------- gate MLP: relu(x@gW1+gb1)@gW2+gb2 -> gate(N); no global atomic ----
__global__ __launch_bounds__(256) void gate_kernel(
        const float* __restrict__ x2, const float* __restrict__ gW1,
        const float* __restrict__ gb1, const float* __restrict__ gW2,
        const float* __restrict__ gb2, float* __restrict__ gate) {
    const int n = blockIdx.x * 4 + (threadIdx.x >> 6);
    const int c = threadIdx.x & 63;
    const float* xr = x2 + (size_t)n * HID;
    float acc = 0.f;
    for (int k = 0; k < HID; ++k) acc = fmaf(xr[k], gW1[k * HID + c], acc);
    float t = acc + gb1[c];
    t = t > 0.f ? t : 0.f;
    float g = t * gW2[c];
#pragma unroll
    for (int off = 32; off > 0; off >>= 1) g += __shfl_down(g, off);
    if (c == 0) gate[n] = g + gb2[0];
}

// -------- hierarchical global max of gate: 48 blocks -> 48 atomics --------
__global__ __launch_bounds__(256) void gmax_kernel(
        const float* __restrict__ gate, unsigned* __restrict__ gmax) {
    float m = -1e30f;
    for (int n = blockIdx.x * 256 + threadIdx.x; n < N_NODES;
         n += gridDim.x * 256)
        m = fmaxf(m, gate[n]);
    __shared__ float red[256];
    red[threadIdx.x] = m;
    __syncthreads();
    for (int s = 128; s > 0; s >>= 1) {
        if (threadIdx.x < s)
            red[threadIdx.x] = fmaxf(red[threadIdx.x], red[threadIdx.x + s]);
        __syncthreads();
    }
    if (threadIdx.x == 0) atomicMax(gmax, fkey(red[0]));
}

// -------- exp(gate - max), block-reduced sum --------
__global__ __launch_bounds__(256) void egate_kernel(
        float* __restrict__ gate, const unsigned* __restrict__ gmax,
        float* __restrict__ gsum) {
    const int n = blockIdx.x * 256 + threadIdx.x;
    float e = 0.f;
    if (n < N_NODES) {
        float m = funkey(*gmax);
        e = expf(gate[n] - m);
        gate[n] = e;
    }
    __shared__ float red[256];
    red[threadIdx.x] = e;
    __syncthreads();
    for (int s = 128; s > 0; s >>= 1) {
        if (threadIdx.x < s) red[threadIdx.x] += red[threadIdx.x + s];
        __syncthreads();
    }
    if (threadIdx.x == 0) atomicAdd(gsum, red[0]);
}

// -------- weighted pooling: out[c] = sum_n egate[n]/gsum * x2[n,c] --------
__global__ __launch_bounds__(256) void final_kernel(
        const float* __restrict__ x2, const float* __restrict__ egate,
        const float* __restrict__ gsum, float* __restrict__ out) {
    const int c   = threadIdx.x & 63;
    const int sub = threadIdx.x >> 6;
    float acc = 0.f;
    for (int n = blockIdx.x * 4 + sub; n < N_NODES; n += gridDim.x * 4)
        acc += egate[n] * x2[(size_t)n * HID + c];
    __shared__ float red[256];
    red[threadIdx.x] = acc;
    __syncthreads();
    if (threadIdx.x < 64) {
        float t = red[threadIdx.x] + red[64 + threadIdx.x] +
                  red[128 + threadIdx.x] + red[192 + threadIdx.x];
        atomicAdd(&out[c], t / (*gsum));
    }
}

extern "C" void kernel_launch(void* const* d_in, const int* in_sizes, int n_in,
                              void* d_out, int out_size, void* d_ws, size_t ws_size,
                              hipStream_t stream) {
    const float* node_feats = (const float*)d_in[0];
    const int*   ei         = (const int*)d_in[1];
    const float* W1   = (const float*)d_in[2];
    const float* as1  = (const float*)d_in[3];
    const float* ad1  = (const float*)d_in[4];
    const float* b1   = (const float*)d_in[5];
    const float* W2   = (const float*)d_in[6];
    const float* as2  = (const float*)d_in[7];
    const float* ad2  = (const float*)d_in[8];
    const float* b2   = (const float*)d_in[9];
    const float* gW1  = (const float*)d_in[10];
    const float* gb1  = (const float*)d_in[11];
    const float* gW2  = (const float*)d_in[12];
    const float* gb2  = (const float*)d_in[13];
    float* out = (float*)d_out;

    // ---- workspace layout (4-byte units) ----
    float* f = (float*)d_ws;
    size_t o = 0;
    float* h1   = f + o; o += (size_t)N_NODES * C1;     // 12.8M
    float* h2   = f + o; o += (size_t)N_NODES * HID;    // 3.2M
    float* x1   = f + o; o += (size_t)N_NODES * C1;     // 12.8M
    float* x2   = f + o; o += (size_t)N_NODES * HID;    // 3.2M
    float* als1 = f + o; o += (size_t)N_NODES * HEADS;
    float* ald1 = f + o; o += (size_t)N_NODES * HEADS;
    float* als2 = f + o; o += N_NODES;
    float* ald2 = f + o; o += N_NODES;
    float* gate = f + o; o += N_NODES;
    int* csr    = (int*)(f + o); o += E_TOT;            // 850K
    int* rowptr = (int*)(f + o); o += N_NODES;
    // ---- contiguous zero region ----
    float* zero0 = f + o;
    int* deg    = (int*)(f + o); o += N_NODES;
    int* cursor = (int*)(f + o); o += N_NODES;
    float* scal = f + o; o += 2;  // [0]=gmax key (uint), [1]=gsum
    size_t zbytes = (size_t)((f + o) - zero0) * sizeof(float);

    hipMemsetAsync(zero0, 0, zbytes, stream);
    hipMemsetAsync(out, 0, (size_t)out_size * sizeof(float), stream);

    const int EB = (E_TOT + 255) / 256;           // 3321

    // ----- CSR build (shared by both layers) -----
    deg_kernel<<<EB, 256, 0, stream>>>(ei, deg);
    scan_kernel<<<1, 1024, 0, stream>>>(deg, rowptr);
    fill_kernel<<<EB, 256, 0, stream>>>(ei, rowptr, cursor, csr);

    // ----- layer 1 -----
    gemm1_kernel<<<N_NODES / 16, 256, 0, stream>>>(node_feats, W1, h1);
    al1_kernel<<<N_NODES, 256, 0, stream>>>(h1, as1, ad1, als1, ald1);
    agg1_kernel<<<N_NODES, 256, 0, stream>>>(csr, rowptr, deg, h1, als1, ald1, x1);
    elu_kernel<255><<<(N_NODES * C1) / 256, 256, 0, stream>>>(x1, b1);

    // ----- layer 2 -----
    gemm2_kernel<<<N_NODES / 16, 256, 0, stream>>>(x1, W2, h2);
    al2_kernel<<<N_NODES / 4, 256, 0, stream>>>(h2, as2, ad2, als2, ald2);
    agg2_kernel<<<N_NODES, 256, 0, stream>>>(csr, rowptr, deg, h2, als2, ald2, x2);
    elu_kernel<63><<<(N_NODES * HID) / 256, 256, 0, stream>>>(x2, b2);

    // ----- attentional pooling -----
    gate_kernel<<<N_NODES / 4, 256, 0, stream>>>(x2, gW1, gb1, gW2, gb2, gate);
    gmax_kernel<<<48, 256, 0, stream>>>(gate, (unsigned*)&scal[0]);
    egate_kernel<<<(N_NODES + 255) / 256, 256, 0, stream>>>(
        gate, (const unsigned*)&scal[0], &scal[1]);
    final_kernel<<<256, 256, 0, stream>>>(x2, gate, &scal[1], out);
}

// Round 9
// 725.232 us; speedup vs baseline: 2.0392x; 1.1958x over previous
//
#include <hip/hip_runtime.h>
#include <hip/hip_bf16.h>
#include <math.h>

#define N_NODES 50000
#define N_EDGES 800000
#define E_TOT   (N_EDGES + N_NODES)   /* 850000, incl. self loops */
#define EMB     384
#define HID     64
#define HEADS   4
#define C1      (HEADS * HID)         /* 256 */
#define CHUNK   256                   /* edges staged per LDS chunk */

typedef unsigned short u16;
typedef __attribute__((ext_vector_type(8))) short bf16x8;
typedef __attribute__((ext_vector_type(4))) float f32x4;

// ---- fp32 <-> bf16 (RNE) ----
__device__ __forceinline__ u16 f2b(float x) {
    unsigned u = __float_as_uint(x);
    return (u16)((u + 0x7FFFu + ((u >> 16) & 1u)) >> 16);
}
__device__ __forceinline__ float b2f(u16 h) {
    return __uint_as_float(((unsigned)h) << 16);
}

// ---- monotone float<->uint key for atomicMax-based float max ----
__device__ __forceinline__ unsigned fkey(float f) {
    unsigned b = __float_as_uint(f);
    return (b & 0x80000000u) ? ~b : (b | 0x80000000u);
}
__device__ __forceinline__ float funkey(unsigned u) {
    return (u & 0x80000000u) ? __uint_as_float(u ^ 0x80000000u)
                             : __uint_as_float(~u);
}

__device__ __forceinline__ void edge_sd(int e, const int* __restrict__ ei,
                                        int& s, int& d) {
    if (e < N_EDGES) { s = ei[e]; d = ei[N_EDGES + e]; }
    else             { s = d = e - N_EDGES; }
}

// ---------------- CSR build (by dst) ----------------
__global__ __launch_bounds__(256) void deg_kernel(const int* __restrict__ ei,
                                                  int* __restrict__ deg) {
    const int e = blockIdx.x * 256 + threadIdx.x;
    if (e >= E_TOT) return;
    int s, d; edge_sd(e, ei, s, d);
    atomicAdd(&deg[d], 1);
}

__global__ __launch_bounds__(1024) void scan_kernel(const int* __restrict__ deg,
                                                    int* __restrict__ rowptr) {
    __shared__ int ts[1024];
    const int t  = threadIdx.x;
    const int CH = (N_NODES + 1023) / 1024;   // 49
    const int st = t * CH;
    const int en = st + CH < N_NODES ? st + CH : N_NODES;
    int s = 0;
    for (int i = st; i < en; ++i) s += deg[i];
    ts[t] = s;
    __syncthreads();
    for (int off = 1; off < 1024; off <<= 1) {
        int v = (t >= off) ? ts[t - off] : 0;
        __syncthreads();
        ts[t] += v;
        __syncthreads();
    }
    int off = ts[t] - s;                      // exclusive prefix
    for (int i = st; i < en; ++i) { rowptr[i] = off; off += deg[i]; }
}

__global__ __launch_bounds__(256) void fill_kernel(const int* __restrict__ ei,
                                                   const int* __restrict__ rowptr,
                                                   int* __restrict__ cursor,
                                                   int* __restrict__ csr) {
    const int e = blockIdx.x * 256 + threadIdx.x;
    if (e >= E_TOT) return;
    int s, d; edge_sd(e, ei, s, d);
    int p = atomicAdd(&cursor[d], 1);
    csr[rowptr[d] + p] = s;
}

// ---- weight convert: W1t[col][k] bf16 (256x384), W2t[col][k] bf16 (64x256) ----
__global__ __launch_bounds__(256) void conv_w_kernel(
        const float* __restrict__ W1, const float* __restrict__ W2,
        u16* __restrict__ W1t, u16* __restrict__ W2t) {
    const int i = blockIdx.x * 256 + threadIdx.x;
    if (i < EMB * C1) {                       // W1: [k][col] row-major
        int k = i >> 8, c = i & 255;
        W1t[c * EMB + k] = f2b(W1[i]);
    }
    if (i < C1 * HID) {                       // W2: [k][col]
        int k = i >> 6, c = i & 63;
        W2t[c * C1 + k] = f2b(W2[i]);
    }
}

// ------------- GEMM1 (MFMA): X(N,384)f32 @ W1t -> Hb(N,256)bf16 -------------
// Block: 64 rows x 256 cols, 4 waves (wave w = cols w*64..+63).
// K staged in chunks of 32 (f32->bf16) into 5KB LDS; B frags from global W1t.
// LDS row stride 40 u16 = 80 B = 16*5: ds_read_b128-aligned, conflict-benign.
__global__ __launch_bounds__(256) void gemm1_mfma(
        const float* __restrict__ X, const u16* __restrict__ W1t,
        u16* __restrict__ Hb) {
    __shared__ u16 As[64][40];
    const int r0 = blockIdx.x * 64;
    const int w  = threadIdx.x >> 6;
    const int l  = threadIdx.x & 63;
    const int lr = l & 15, lg = l >> 4;
    f32x4 acc[4][4] = {};                     // [row-tile][col-tile]
    for (int k0 = 0; k0 < EMB; k0 += 32) {
        __syncthreads();
#pragma unroll
        for (int it = 0; it < 2; ++it) {
            int i   = threadIdx.x + it * 256; // 0..511
            int row = i >> 3, kq = (i & 7) * 4;
            int grow = r0 + row;
            float4 v = (grow < N_NODES)
                ? *(const float4*)&X[(size_t)grow * EMB + k0 + kq]
                : make_float4(0.f, 0.f, 0.f, 0.f);
            uint2 p;
            p.x = (unsigned)f2b(v.x) | ((unsigned)f2b(v.y) << 16);
            p.y = (unsigned)f2b(v.z) | ((unsigned)f2b(v.w) << 16);
            *(uint2*)&As[row][kq] = p;
        }
        __syncthreads();
        const u16* wp = W1t + (size_t)(w * 64 + lr) * EMB + k0 + lg * 8;
        bf16x8 bfr[4], afr[4];
        bfr[0] = *(const bf16x8*)(wp);
        bfr[1] = *(const bf16x8*)(wp + 16 * EMB);
        bfr[2] = *(const bf16x8*)(wp + 32 * EMB);
        bfr[3] = *(const bf16x8*)(wp + 48 * EMB);
#pragma unroll
        for (int rt = 0; rt < 4; ++rt)
            afr[rt] = *(const bf16x8*)&As[rt * 16 + lr][lg * 8];
#pragma unroll
        for (int rt = 0; rt < 4; ++rt)
#pragma unroll
            for (int ct = 0; ct < 4; ++ct)
                acc[rt][ct] = __builtin_amdgcn_mfma_f32_16x16x32_bf16(
                    afr[rt], bfr[ct], acc[rt][ct], 0, 0, 0);
    }
#pragma unroll
    for (int rt = 0; rt < 4; ++rt)
#pragma unroll
        for (int reg = 0; reg < 4; ++reg) {
            int row = r0 + rt * 16 + lg * 4 + reg;
            if (row < N_NODES) {
#pragma unroll
                for (int ct = 0; ct < 4; ++ct)
                    Hb[(size_t)row * C1 + w * 64 + ct * 16 + lr] =
                        f2b(acc[rt][ct][reg]);
            }
        }
}

// ------------- GEMM2 (MFMA): x1b(N,256)bf16 @ W2t -> h2b(N,64)bf16 ----------
// Block: 64 rows x 64 cols, 4 waves (wave w = cols w*16..+15).
__global__ __launch_bounds__(256) void gemm2_mfma(
        const u16* __restrict__ Xb, const u16* __restrict__ W2t,
        u16* __restrict__ Hb) {
    __shared__ u16 As[64][40];
    const int r0 = blockIdx.x * 64;
    const int w  = threadIdx.x >> 6;
    const int l  = threadIdx.x & 63;
    const int lr = l & 15, lg = l >> 4;
    f32x4 acc[4] = {};                        // [row-tile]
    for (int k0 = 0; k0 < C1; k0 += 32) {
        __syncthreads();
        {
            int i   = threadIdx.x;            // 0..255 (64 rows x 4 x 8 bf16)
            int row = i >> 2, kq = (i & 3) * 8;
            int grow = r0 + row;
            uint4 v = (grow < N_NODES)
                ? *(const uint4*)&Xb[(size_t)grow * C1 + k0 + kq]
                : make_uint4(0u, 0u, 0u, 0u);
            *(uint4*)&As[row][kq] = v;
        }
        __syncthreads();
        bf16x8 bfr = *(const bf16x8*)&W2t[(size_t)(w * 16 + lr) * C1 + k0 + lg * 8];
#pragma unroll
        for (int rt = 0; rt < 4; ++rt) {
            bf16x8 afr = *(const bf16x8*)&As[rt * 16 + lr][lg * 8];
            acc[rt] = __builtin_amdgcn_mfma_f32_16x16x32_bf16(
                afr, bfr, acc[rt], 0, 0, 0);
        }
    }
#pragma unroll
    for (int rt = 0; rt < 4; ++rt)
#pragma unroll
        for (int reg = 0; reg < 4; ++reg) {
            int row = r0 + rt * 16 + lg * 4 + reg;
            if (row < N_NODES)
                Hb[(size_t)row * HID + w * 16 + lr] = f2b(acc[rt][reg]);
        }
}

// -------- attention logits layer1: als/ald (N,4), from bf16 h --------
__global__ __launch_bounds__(256) void al1_kernel(
        const u16* __restrict__ Hb, const float* __restrict__ as_,
        const float* __restrict__ ad_, float* __restrict__ als,
        float* __restrict__ ald) {
    const int n = blockIdx.x;
    const int h = threadIdx.x >> 6;
    const int c = threadIdx.x & 63;
    float v = b2f(Hb[(size_t)n * C1 + h * HID + c]);
    float s = v * as_[h * HID + c];
    float d = v * ad_[h * HID + c];
#pragma unroll
    for (int off = 32; off > 0; off >>= 1) {
        s += __shfl_down(s, off);
        d += __shfl_down(d, off);
    }
    if (c == 0) { als[n * HEADS + h] = s; ald[n * HEADS + h] = d; }
}

// -------- layer2 logits: 1 head, 4 nodes per block, bf16 h --------
__global__ __launch_bounds__(256) void al2_kernel(
        const u16* __restrict__ Hb, const float* __restrict__ as_,
        const float* __restrict__ ad_, float* __restrict__ als,
        float* __restrict__ ald) {
    const int n = blockIdx.x * 4 + (threadIdx.x >> 6);
    const int c = threadIdx.x & 63;
    float v = b2f(Hb[(size_t)n * HID + c]);
    float s = v * as_[c];
    float d = v * ad_[c];
#pragma unroll
    for (int off = 32; off > 0; off >>= 1) {
        s += __shfl_down(s, off);
        d += __shfl_down(d, off);
    }
    if (c == 0) { als[n] = s; ald[n] = d; }
}

// ---- layer1 fused softmax+aggregate: block per dst; bf16 h gather ----
__global__ __launch_bounds__(256) void agg1_kernel(
        const int* __restrict__ csr, const int* __restrict__ rowptr,
        const int* __restrict__ deg, const u16* __restrict__ Hb,
        const float* __restrict__ als, const float* __restrict__ ald,
        float* __restrict__ xout) {
    __shared__ float alpha_s[CHUNK][5];
    __shared__ int   src_s[CHUNK];
    __shared__ float red_s[4][C1];
    const int d = blockIdx.x;
    const int w = threadIdx.x >> 6;
    const int c = threadIdx.x & 63;
    const int row = rowptr[d];
    const int dg  = deg[d];
    const float aldv = ald[d * HEADS + w];
    float lmax = -1e30f;
    for (int j = c; j < dg; j += 64) {
        int s = csr[row + j];
        float l = als[s * HEADS + w] + aldv;
        l = l > 0.f ? l : 0.2f * l;
        lmax = fmaxf(lmax, l);
    }
#pragma unroll
    for (int off = 32; off > 0; off >>= 1)
        lmax = fmaxf(lmax, __shfl_xor(lmax, off));
    float lsum = 0.f;
    for (int j = c; j < dg; j += 64) {
        int s = csr[row + j];
        float l = als[s * HEADS + w] + aldv;
        l = l > 0.f ? l : 0.2f * l;
        lsum += expf(l - lmax);
    }
#pragma unroll
    for (int off = 32; off > 0; off >>= 1) lsum += __shfl_xor(lsum, off);
    const float inv = 1.f / (lsum + 1e-16f);

    // gather: lane c holds channels 4c..4c+3 (head = c>>4)
    float4 acc = make_float4(0.f, 0.f, 0.f, 0.f);
    const int myh = c >> 4;
    for (int base = 0; base < dg; base += CHUNK) {
        const int cn = (dg - base) < CHUNK ? (dg - base) : CHUNK;
        for (int j = c; j < cn; j += 64) {
            int s = csr[row + base + j];
            if (w == 0) src_s[j] = s;
            float l = als[s * HEADS + w] + aldv;
            l = l > 0.f ? l : 0.2f * l;
            alpha_s[j][w] = expf(l - lmax) * inv;
        }
        __syncthreads();
        for (int j = w; j < cn; j += 4) {
            int s = src_s[j];
            float a = alpha_s[j][myh];
            uint2 v = *(const uint2*)&Hb[(size_t)s * C1 + c * 4];
            acc.x = fmaf(a, __uint_as_float(v.x << 16), acc.x);
            acc.y = fmaf(a, __uint_as_float(v.x & 0xFFFF0000u), acc.y);
            acc.z = fmaf(a, __uint_as_float(v.y << 16), acc.z);
            acc.w = fmaf(a, __uint_as_float(v.y & 0xFFFF0000u), acc.w);
        }
        __syncthreads();
    }
    *(float4*)&red_s[w][c * 4] = acc;
    __syncthreads();
    float r = red_s[0][threadIdx.x] + red_s[1][threadIdx.x] +
              red_s[2][threadIdx.x] + red_s[3][threadIdx.x];
    xout[(size_t)d * C1 + threadIdx.x] = r;
}

// ---- layer2 fused softmax+aggregate: block per dst, bf16 h --------
__global__ __launch_bounds__(256) void agg2_kernel(
        const int* __restrict__ csr, const int* __restrict__ rowptr,
        const int* __restrict__ deg, const u16* __restrict__ Hb,
        const float* __restrict__ als, const float* __restrict__ ald,
        float* __restrict__ xout) {
    __shared__ float alpha_s[CHUNK];
    __shared__ int   src_s[CHUNK];
    __shared__ float red_s[4][HID];
    const int d = blockIdx.x;
    const int w = threadIdx.x >> 6;
    const int c = threadIdx.x & 63;
    const int row = rowptr[d];
    const int dg  = deg[d];
    const float aldv = ald[d];
    float lmax = -1e30f;
    for (int j = c; j < dg; j += 64) {
        int s = csr[row + j];
        float l = als[s] + aldv;
        l = l > 0.f ? l : 0.2f * l;
        lmax = fmaxf(lmax, l);
    }
#pragma unroll
    for (int off = 32; off > 0; off >>= 1)
        lmax = fmaxf(lmax, __shfl_xor(lmax, off));
    float lsum = 0.f;
    for (int j = c; j < dg; j += 64) {
        int s = csr[row + j];
        float l = als[s] + aldv;
        l = l > 0.f ? l : 0.2f * l;
        lsum += expf(l - lmax);
    }
#pragma unroll
    for (int off = 32; off > 0; off >>= 1) lsum += __shfl_xor(lsum, off);
    const float inv = 1.f / (lsum + 1e-16f);

    float acc = 0.f;
    for (int base = 0; base < dg; base += CHUNK) {
        const int cn = (dg - base) < CHUNK ? (dg - base) : CHUNK;
        for (int j = threadIdx.x; j < cn; j += 256) {
            int s = csr[row + base + j];
            src_s[j] = s;
            float l = als[s] + aldv;
            l = l > 0.f ? l : 0.2f * l;
            alpha_s[j] = expf(l - lmax) * inv;
        }
        __syncthreads();
        for (int j = w; j < cn; j += 4)
            acc = fmaf(alpha_s[j], b2f(Hb[(size_t)src_s[j] * HID + c]), acc);
        __syncthreads();
    }
    red_s[w][c] = acc;
    __syncthreads();
    if (threadIdx.x < HID) {
        float r = red_s[0][threadIdx.x] + red_s[1][threadIdx.x] +
                  red_s[2][threadIdx.x] + red_s[3][threadIdx.x];
        xout[(size_t)d * HID + threadIdx.x] = r;
    }
}

// -------- layer1 bias + ELU: x1 f32 -> x1b bf16 --------
__global__ __launch_bounds__(256) void elu1_kernel(
        const float* __restrict__ x, const float* __restrict__ b,
        u16* __restrict__ xb) {
    const size_t i = (size_t)blockIdx.x * 256 + threadIdx.x;
    float v = x[i] + b[i & 255];
    v = v > 0.f ? v : expm1f(v);
    xb[i] = f2b(v);
}

// -------- layer2 bias + ELU, in place (f32) --------
__global__ __launch_bounds__(256) void elu2_kernel(float* __restrict__ x,
                                                   const float* __restrict__ b) {
    const size_t i = (size_t)blockIdx.x * 256 + threadIdx.x;
    float v = x[i] + b[i & 63];
    x[i] = v > 0.f ? v : expm1f(v);
}

// -------- gate MLP: relu(x@gW1+gb1)@gW2+gb2 -> gate(N) --------
__global__ __launch_bounds__(256) void gate_kernel(
        const float* __restrict__ x2, const float* __restrict__ gW1,
        const float* __restrict__ gb1, const float* __restrict__ gW2,
        const float* __restrict__ gb2, float* __restrict__ gate) {
    const int n = blockIdx.x * 4 + (threadIdx.x >> 6);
    const int c = threadIdx.x & 63;
    const float* xr = x2 + (size_t)n * HID;
    float acc = 0.f;
    for (int k = 0; k < HID; ++k) acc = fmaf(xr[k], gW1[k * HID + c], acc);
    float t = acc + gb1[c];
    t = t > 0.f ? t : 0.f;
    float g = t * gW2[c];
#pragma unroll
    for (int off = 32; off > 0; off >>= 1) g += __shfl_down(g, off);
    if (c == 0) gate[n] = g + gb2[0];
}

// -------- hierarchical global max of gate --------
__global__ __launch_bounds__(256) void gmax_kernel(
        const float* __restrict__ gate, unsigned* __restrict__ gmax) {
    float m = -1e30f;
    for (int n = blockIdx.x * 256 + threadIdx.x; n < N_NODES;
         n += gridDim.x * 256)
        m = fmaxf(m, gate[n]);
    __shared__ float red[256];
    red[threadIdx.x] = m;
    __syncthreads();
    for (int s = 128; s > 0; s >>= 1) {
        if (threadIdx.x < s)
            red[threadIdx.x] = fmaxf(red[threadIdx.x], red[threadIdx.x + s]);
        __syncthreads();
    }
    if (threadIdx.x == 0) atomicMax(gmax, fkey(red[0]));
}

// -------- exp(gate - max), block-reduced sum --------
__global__ __launch_bounds__(256) void egate_kernel(
        float* __restrict__ gate, const unsigned* __restrict__ gmax,
        float* __restrict__ gsum) {
    const int n = blockIdx.x * 256 + threadIdx.x;
    float e = 0.f;
    if (n < N_NODES) {
        float m = funkey(*gmax);
        e = expf(gate[n] - m);
        gate[n] = e;
    }
    __shared__ float red[256];
    red[threadIdx.x] = e;
    __syncthreads();
    for (int s = 128; s > 0; s >>= 1) {
        if (threadIdx.x < s) red[threadIdx.x] += red[threadIdx.x + s];
        __syncthreads();
    }
    if (threadIdx.x == 0) atomicAdd(gsum, red[0]);
}

// -------- weighted pooling --------
__global__ __launch_bounds__(256) void final_kernel(
        const float* __restrict__ x2, const float* __restrict__ egate,
        const float* __restrict__ gsum, float* __restrict__ out) {
    const int c   = threadIdx.x & 63;
    const int sub = threadIdx.x >> 6;
    float acc = 0.f;
    for (int n = blockIdx.x * 4 + sub; n < N_NODES; n += gridDim.x * 4)
        acc += egate[n] * x2[(size_t)n * HID + c];
    __shared__ float red[256];
    red[threadIdx.x] = acc;
    __syncthreads();
    if (threadIdx.x < 64) {
        float t = red[threadIdx.x] + red[64 + threadIdx.x] +
                  red[128 + threadIdx.x] + red[192 + threadIdx.x];
        atomicAdd(&out[c], t / (*gsum));
    }
}

extern "C" void kernel_launch(void* const* d_in, const int* in_sizes, int n_in,
                              void* d_out, int out_size, void* d_ws, size_t ws_size,
                              hipStream_t stream) {
    const float* node_feats = (const float*)d_in[0];
    const int*   ei         = (const int*)d_in[1];
    const float* W1   = (const float*)d_in[2];
    const float* as1  = (const float*)d_in[3];
    const float* ad1  = (const float*)d_in[4];
    const float* b1   = (const float*)d_in[5];
    const float* W2   = (const float*)d_in[6];
    const float* as2  = (const float*)d_in[7];
    const float* ad2  = (const float*)d_in[8];
    const float* b2   = (const float*)d_in[9];
    const float* gW1  = (const float*)d_in[10];
    const float* gb1  = (const float*)d_in[11];
    const float* gW2  = (const float*)d_in[12];
    const float* gb2  = (const float*)d_in[13];
    float* out = (float*)d_out;

    // ---- workspace layout (4-byte units) ----
    float* f = (float*)d_ws;
    size_t o = 0;
    float* x1   = f + o; o += (size_t)N_NODES * C1;      // f32
    float* x2   = f + o; o += (size_t)N_NODES * HID;     // f32
    float* als1 = f + o; o += (size_t)N_NODES * HEADS;
    float* ald1 = f + o; o += (size_t)N_NODES * HEADS;
    float* als2 = f + o; o += N_NODES;
    float* ald2 = f + o; o += N_NODES;
    float* gate = f + o; o += N_NODES;
    int* csr    = (int*)(f + o); o += E_TOT;
    int* rowptr = (int*)(f + o); o += N_NODES;
    u16* h1b    = (u16*)(f + o); o += (size_t)N_NODES * C1 / 2;   // bf16
    u16* x1b    = (u16*)(f + o); o += (size_t)N_NODES * C1 / 2;   // bf16
    u16* h2b    = (u16*)(f + o); o += (size_t)N_NODES * HID / 2;  // bf16
    u16* W1t    = (u16*)(f + o); o += (size_t)EMB * C1 / 2;
    u16* W2t    = (u16*)(f + o); o += (size_t)C1 * HID / 2;
    // ---- contiguous zero region ----
    float* zero0 = f + o;
    int* deg    = (int*)(f + o); o += N_NODES;
    int* cursor = (int*)(f + o); o += N_NODES;
    float* scal = f + o; o += 2;  // [0]=gmax key (uint), [1]=gsum
    size_t zbytes = (size_t)((f + o) - zero0) * sizeof(float);

    hipMemsetAsync(zero0, 0, zbytes, stream);
    hipMemsetAsync(out, 0, (size_t)out_size * sizeof(float), stream);

    const int EB = (E_TOT + 255) / 256;            // 3321
    const int GB = (N_NODES + 63) / 64;            // 782

    // ----- CSR build + weight convert -----
    conv_w_kernel<<<(EMB * C1 + 255) / 256, 256, 0, stream>>>(W1, W2, W1t, W2t);
    deg_kernel<<<EB, 256, 0, stream>>>(ei, deg);
    scan_kernel<<<1, 1024, 0, stream>>>(deg, rowptr);
    fill_kernel<<<EB, 256, 0, stream>>>(ei, rowptr, cursor, csr);

    // ----- layer 1 -----
    gemm1_mfma<<<GB, 256, 0, stream>>>(node_feats, W1t, h1b);
    al1_kernel<<<N_NODES, 256, 0, stream>>>(h1b, as1, ad1, als1, ald1);
    agg1_kernel<<<N_NODES, 256, 0, stream>>>(csr, rowptr, deg, h1b, als1, ald1, x1);
    elu1_kernel<<<(N_NODES * C1) / 256, 256, 0, stream>>>(x1, b1, x1b);

    // ----- layer 2 -----
    gemm2_mfma<<<GB, 256, 0, stream>>>(x1b, W2t, h2b);
    al2_kernel<<<N_NODES / 4, 256, 0, stream>>>(h2b, as2, ad2, als2, ald2);
    agg2_kernel<<<N_NODES, 256, 0, stream>>>(csr, rowptr, deg, h2b, als2, ald2, x2);
    elu2_kernel<<<(N_NODES * HID) / 256, 256, 0, stream>>>(x2, b2);

    // ----- attentional pooling -----
    gate_kernel<<<N_NODES / 4, 256, 0, stream>>>(x2, gW1, gb1, gW2, gb2, gate);
    gmax_kernel<<<48, 256, 0, stream>>>(gate, (unsigned*)&scal[0]);
    egate_kernel<<<(N_NODES + 255) / 256, 256, 0, stream>>>(
        gate, (const unsigned*)&scal[0], &scal[1]);
    final_kernel<<<256, 256, 0, stream>>>(x2, gate, &scal[1], out);
}

// Round 10
// 657.335 us; speedup vs baseline: 2.2498x; 1.1033x over previous
//
#include <hip/hip_runtime.h>
#include <hip/hip_bf16.h>
#include <math.h>

#define N_NODES 50000
#define N_EDGES 800000
#define E_TOT   (N_EDGES + N_NODES)   /* 850000, incl. self loops */
#define EMB     384
#define HID     64
#define HEADS   4
#define C1      (HEADS * HID)         /* 256 */
#define CHUNK   256                   /* edges staged per LDS chunk */

typedef unsigned short u16;
typedef __attribute__((ext_vector_type(8))) short bf16x8;
typedef __attribute__((ext_vector_type(4))) float f32x4;

// ---- fp32 <-> bf16 (RNE) ----
__device__ __forceinline__ u16 f2b(float x) {
    unsigned u = __float_as_uint(x);
    return (u16)((u + 0x7FFFu + ((u >> 16) & 1u)) >> 16);
}
__device__ __forceinline__ float b2f(u16 h) {
    return __uint_as_float(((unsigned)h) << 16);
}

// ---- monotone float<->uint key for atomicMax-based float max ----
__device__ __forceinline__ unsigned fkey(float f) {
    unsigned b = __float_as_uint(f);
    return (b & 0x80000000u) ? ~b : (b | 0x80000000u);
}
__device__ __forceinline__ float funkey(unsigned u) {
    return (u & 0x80000000u) ? __uint_as_float(u ^ 0x80000000u)
                             : __uint_as_float(~u);
}

__device__ __forceinline__ void edge_sd(int e, const int* __restrict__ ei,
                                        int& s, int& d) {
    if (e < N_EDGES) { s = ei[e]; d = ei[N_EDGES + e]; }
    else             { s = d = e - N_EDGES; }
}

// ---------------- CSR build (by dst) ----------------
__global__ __launch_bounds__(256) void deg_kernel(const int* __restrict__ ei,
                                                  int* __restrict__ deg) {
    const int e = blockIdx.x * 256 + threadIdx.x;
    if (e >= E_TOT) return;
    int s, d; edge_sd(e, ei, s, d);
    atomicAdd(&deg[d], 1);
}

__global__ __launch_bounds__(1024) void scan_kernel(const int* __restrict__ deg,
                                                    int* __restrict__ rowptr) {
    __shared__ int ts[1024];
    const int t  = threadIdx.x;
    const int CH = (N_NODES + 1023) / 1024;   // 49
    const int st = t * CH;
    const int en = st + CH < N_NODES ? st + CH : N_NODES;
    int s = 0;
    for (int i = st; i < en; ++i) s += deg[i];
    ts[t] = s;
    __syncthreads();
    for (int off = 1; off < 1024; off <<= 1) {
        int v = (t >= off) ? ts[t - off] : 0;
        __syncthreads();
        ts[t] += v;
        __syncthreads();
    }
    int off = ts[t] - s;                      // exclusive prefix
    for (int i = st; i < en; ++i) { rowptr[i] = off; off += deg[i]; }
}

__global__ __launch_bounds__(256) void fill_kernel(const int* __restrict__ ei,
                                                   const int* __restrict__ rowptr,
                                                   int* __restrict__ cursor,
                                                   int* __restrict__ csr) {
    const int e = blockIdx.x * 256 + threadIdx.x;
    if (e >= E_TOT) return;
    int s, d; edge_sd(e, ei, s, d);
    int p = atomicAdd(&cursor[d], 1);
    csr[rowptr[d] + p] = s;
}

// ---- weight convert: W1t[col][k] bf16 (256x384), W2t[col][k] bf16 (64x256) ----
__global__ __launch_bounds__(256) void conv_w_kernel(
        const float* __restrict__ W1, const float* __restrict__ W2,
        u16* __restrict__ W1t, u16* __restrict__ W2t) {
    const int i = blockIdx.x * 256 + threadIdx.x;
    if (i < EMB * C1) {                       // W1: [k][col] row-major
        int k = i >> 8, c = i & 255;
        W1t[c * EMB + k] = f2b(W1[i]);
    }
    if (i < C1 * HID) {                       // W2: [k][col]
        int k = i >> 6, c = i & 63;
        W2t[c * C1 + k] = f2b(W2[i]);
    }
}

// ------------- GEMM1 (MFMA): X(N,384)f32 @ W1t -> Hb(N,256)bf16 -------------
__global__ __launch_bounds__(256) void gemm1_mfma(
        const float* __restrict__ X, const u16* __restrict__ W1t,
        u16* __restrict__ Hb) {
    __shared__ u16 As[64][40];
    const int r0 = blockIdx.x * 64;
    const int w  = threadIdx.x >> 6;
    const int l  = threadIdx.x & 63;
    const int lr = l & 15, lg = l >> 4;
    f32x4 acc[4][4] = {};                     // [row-tile][col-tile]
    for (int k0 = 0; k0 < EMB; k0 += 32) {
        __syncthreads();
#pragma unroll
        for (int it = 0; it < 2; ++it) {
            int i   = threadIdx.x + it * 256; // 0..511
            int row = i >> 3, kq = (i & 7) * 4;
            int grow = r0 + row;
            float4 v = (grow < N_NODES)
                ? *(const float4*)&X[(size_t)grow * EMB + k0 + kq]
                : make_float4(0.f, 0.f, 0.f, 0.f);
            uint2 p;
            p.x = (unsigned)f2b(v.x) | ((unsigned)f2b(v.y) << 16);
            p.y = (unsigned)f2b(v.z) | ((unsigned)f2b(v.w) << 16);
            *(uint2*)&As[row][kq] = p;
        }
        __syncthreads();
        const u16* wp = W1t + (size_t)(w * 64 + lr) * EMB + k0 + lg * 8;
        bf16x8 bfr[4], afr[4];
        bfr[0] = *(const bf16x8*)(wp);
        bfr[1] = *(const bf16x8*)(wp + 16 * EMB);
        bfr[2] = *(const bf16x8*)(wp + 32 * EMB);
        bfr[3] = *(const bf16x8*)(wp + 48 * EMB);
#pragma unroll
        for (int rt = 0; rt < 4; ++rt)
            afr[rt] = *(const bf16x8*)&As[rt * 16 + lr][lg * 8];
#pragma unroll
        for (int rt = 0; rt < 4; ++rt)
#pragma unroll
            for (int ct = 0; ct < 4; ++ct)
                acc[rt][ct] = __builtin_amdgcn_mfma_f32_16x16x32_bf16(
                    afr[rt], bfr[ct], acc[rt][ct], 0, 0, 0);
    }
#pragma unroll
    for (int rt = 0; rt < 4; ++rt)
#pragma unroll
        for (int reg = 0; reg < 4; ++reg) {
            int row = r0 + rt * 16 + lg * 4 + reg;
            if (row < N_NODES) {
#pragma unroll
                for (int ct = 0; ct < 4; ++ct)
                    Hb[(size_t)row * C1 + w * 64 + ct * 16 + lr] =
                        f2b(acc[rt][ct][reg]);
            }
        }
}

// ------------- GEMM2 (MFMA): x1b(N,256)bf16 @ W2t -> h2b(N,64)bf16 ----------
__global__ __launch_bounds__(256) void gemm2_mfma(
        const u16* __restrict__ Xb, const u16* __restrict__ W2t,
        u16* __restrict__ Hb) {
    __shared__ u16 As[64][40];
    const int r0 = blockIdx.x * 64;
    const int w  = threadIdx.x >> 6;
    const int l  = threadIdx.x & 63;
    const int lr = l & 15, lg = l >> 4;
    f32x4 acc[4] = {};                        // [row-tile]
    for (int k0 = 0; k0 < C1; k0 += 32) {
        __syncthreads();
        {
            int i   = threadIdx.x;            // 0..255 (64 rows x 4 x 8 bf16)
            int row = i >> 2, kq = (i & 3) * 8;
            int grow = r0 + row;
            uint4 v = (grow < N_NODES)
                ? *(const uint4*)&Xb[(size_t)grow * C1 + k0 + kq]
                : make_uint4(0u, 0u, 0u, 0u);
            *(uint4*)&As[row][kq] = v;
        }
        __syncthreads();
        bf16x8 bfr = *(const bf16x8*)&W2t[(size_t)(w * 16 + lr) * C1 + k0 + lg * 8];
#pragma unroll
        for (int rt = 0; rt < 4; ++rt) {
            bf16x8 afr = *(const bf16x8*)&As[rt * 16 + lr][lg * 8];
            acc[rt] = __builtin_amdgcn_mfma_f32_16x16x32_bf16(
                afr, bfr, acc[rt], 0, 0, 0);
        }
    }
#pragma unroll
    for (int rt = 0; rt < 4; ++rt)
#pragma unroll
        for (int reg = 0; reg < 4; ++reg) {
            int row = r0 + rt * 16 + lg * 4 + reg;
            if (row < N_NODES)
                Hb[(size_t)row * HID + w * 16 + lr] = f2b(acc[rt][reg]);
        }
}

// -------- attention logits layer1: als/ald (N,4), from bf16 h --------
__global__ __launch_bounds__(256) void al1_kernel(
        const u16* __restrict__ Hb, const float* __restrict__ as_,
        const float* __restrict__ ad_, float* __restrict__ als,
        float* __restrict__ ald) {
    const int n = blockIdx.x;
    const int h = threadIdx.x >> 6;
    const int c = threadIdx.x & 63;
    float v = b2f(Hb[(size_t)n * C1 + h * HID + c]);
    float s = v * as_[h * HID + c];
    float d = v * ad_[h * HID + c];
#pragma unroll
    for (int off = 32; off > 0; off >>= 1) {
        s += __shfl_down(s, off);
        d += __shfl_down(d, off);
    }
    if (c == 0) { als[n * HEADS + h] = s; ald[n * HEADS + h] = d; }
}

// -------- layer2 logits: 1 head, 4 nodes per block, bf16 h --------
__global__ __launch_bounds__(256) void al2_kernel(
        const u16* __restrict__ Hb, const float* __restrict__ as_,
        const float* __restrict__ ad_, float* __restrict__ als,
        float* __restrict__ ald) {
    const int n = blockIdx.x * 4 + (threadIdx.x >> 6);
    const int c = threadIdx.x & 63;
    float v = b2f(Hb[(size_t)n * HID + c]);
    float s = v * as_[c];
    float d = v * ad_[c];
#pragma unroll
    for (int off = 32; off > 0; off >>= 1) {
        s += __shfl_down(s, off);
        d += __shfl_down(d, off);
    }
    if (c == 0) { als[n] = s; ald[n] = d; }
}

// ---- layer1 fused softmax+aggregate+bias+ELU: block per dst ----
// Single-pass no-max softmax: softmax is shift-invariant and logits are
// bounded (~|10|) so exp() cannot overflow fp32; clamp at 60 as exact guard.
// Stage unnormalized p=exp(l) in LDS (wave w = head w), accumulate lsum
// per head on the fly, gather with p, normalize once in the epilogue.
// Epilogue also fuses +b1 and ELU, writing bf16 x1b directly.
__global__ __launch_bounds__(256) void agg1_kernel(
        const int* __restrict__ csr, const int* __restrict__ rowptr,
        const int* __restrict__ deg, const u16* __restrict__ Hb,
        const float* __restrict__ als, const float* __restrict__ ald,
        const float* __restrict__ b1, u16* __restrict__ xb) {
    __shared__ float alpha_s[CHUNK][5];
    __shared__ int   src_s[CHUNK];
    __shared__ float red_s[4][C1];
    __shared__ float lsum_s[4];
    const int d = blockIdx.x;
    const int w = threadIdx.x >> 6;
    const int c = threadIdx.x & 63;
    const int row = rowptr[d];
    const int dg  = deg[d];
    const float aldv = ald[d * HEADS + w];
    const int myh = c >> 4;

    float4 acc = make_float4(0.f, 0.f, 0.f, 0.f);
    float lsum = 0.f;                          // head-w partial (this wave)
    for (int base = 0; base < dg; base += CHUNK) {
        const int cn = (dg - base) < CHUNK ? (dg - base) : CHUNK;
        // stage: wave w computes unnormalized p for head w; wave 0 stages src
        for (int j = c; j < cn; j += 64) {
            int s = csr[row + base + j];
            if (w == 0) src_s[j] = s;
            float l = als[s * HEADS + w] + aldv;
            l = l > 0.f ? l : 0.2f * l;        // LeakyReLU(0.2)
            float p = expf(fminf(l, 60.f));
            alpha_s[j][w] = p;
            lsum += p;
        }
        __syncthreads();
        // gather: lane c holds channels 4c..4c+3 (head = c>>4)
        for (int j = w; j < cn; j += 4) {
            int s = src_s[j];
            float a = alpha_s[j][myh];
            uint2 v = *(const uint2*)&Hb[(size_t)s * C1 + c * 4];
            acc.x = fmaf(a, __uint_as_float(v.x << 16), acc.x);
            acc.y = fmaf(a, __uint_as_float(v.x & 0xFFFF0000u), acc.y);
            acc.z = fmaf(a, __uint_as_float(v.y << 16), acc.z);
            acc.w = fmaf(a, __uint_as_float(v.y & 0xFFFF0000u), acc.w);
        }
        __syncthreads();
    }
#pragma unroll
    for (int off = 32; off > 0; off >>= 1) lsum += __shfl_xor(lsum, off);
    if (c == 0) lsum_s[w] = lsum;
    *(float4*)&red_s[w][c * 4] = acc;
    __syncthreads();
    // epilogue: col = threadIdx.x, its head = threadIdx.x>>6 == w
    float r = red_s[0][threadIdx.x] + red_s[1][threadIdx.x] +
              red_s[2][threadIdx.x] + red_s[3][threadIdx.x];
    r = r / (lsum_s[w] + 1e-16f) + b1[threadIdx.x];
    r = r > 0.f ? r : expm1f(r);               // ELU
    xb[(size_t)d * C1 + threadIdx.x] = f2b(r);
}

// ---- layer2 fused softmax+aggregate+bias+ELU: block per dst, 1 head ----
__global__ __launch_bounds__(256) void agg2_kernel(
        const int* __restrict__ csr, const int* __restrict__ rowptr,
        const int* __restrict__ deg, const u16* __restrict__ Hb,
        const float* __restrict__ als, const float* __restrict__ ald,
        const float* __restrict__ b2, float* __restrict__ xout) {
    __shared__ float alpha_s[CHUNK];
    __shared__ int   src_s[CHUNK];
    __shared__ float red_s[4][HID];
    __shared__ float lsum_s[4];
    const int d = blockIdx.x;
    const int w = threadIdx.x >> 6;
    const int c = threadIdx.x & 63;
    const int row = rowptr[d];
    const int dg  = deg[d];
    const float aldv = ald[d];

    float acc = 0.f;
    float lsum = 0.f;                          // per-thread partial
    for (int base = 0; base < dg; base += CHUNK) {
        const int cn = (dg - base) < CHUNK ? (dg - base) : CHUNK;
        for (int j = threadIdx.x; j < cn; j += 256) {
            int s = csr[row + base + j];
            src_s[j] = s;
            float l = als[s] + aldv;
            l = l > 0.f ? l : 0.2f * l;
            float p = expf(fminf(l, 60.f));
            alpha_s[j] = p;
            lsum += p;
        }
        __syncthreads();
        for (int j = w; j < cn; j += 4)
            acc = fmaf(alpha_s[j], b2f(Hb[(size_t)src_s[j] * HID + c]), acc);
        __syncthreads();
    }
#pragma unroll
    for (int off = 32; off > 0; off >>= 1) lsum += __shfl_xor(lsum, off);
    if (c == 0) lsum_s[w] = lsum;
    red_s[w][c] = acc;
    __syncthreads();
    if (threadIdx.x < HID) {
        float ls = lsum_s[0] + lsum_s[1] + lsum_s[2] + lsum_s[3];
        float r = red_s[0][threadIdx.x] + red_s[1][threadIdx.x] +
                  red_s[2][threadIdx.x] + red_s[3][threadIdx.x];
        r = r / (ls + 1e-16f) + b2[threadIdx.x];
        r = r > 0.f ? r : expm1f(r);           // ELU
        xout[(size_t)d * HID + threadIdx.x] = r;
    }
}

// -------- gate MLP: relu(x@gW1+gb1)@gW2+gb2 -> gate(N) --------
__global__ __launch_bounds__(256) void gate_kernel(
        const float* __restrict__ x2, const float* __restrict__ gW1,
        const float* __restrict__ gb1, const float* __restrict__ gW2,
        const float* __restrict__ gb2, float* __restrict__ gate) {
    const int n = blockIdx.x * 4 + (threadIdx.x >> 6);
    const int c = threadIdx.x & 63;
    const float* xr = x2 + (size_t)n * HID;
    float acc = 0.f;
    for (int k = 0; k < HID; ++k) acc = fmaf(xr[k], gW1[k * HID + c], acc);
    float t = acc + gb1[c];
    t = t > 0.f ? t : 0.f;
    float g = t * gW2[c];
#pragma unroll
    for (int off = 32; off > 0; off >>= 1) g += __shfl_down(g, off);
    if (c == 0) gate[n] = g + gb2[0];
}

// -------- hierarchical global max of gate --------
__global__ __launch_bounds__(256) void gmax_kernel(
        const float* __restrict__ gate, unsigned* __restrict__ gmax) {
    float m = -1e30f;
    for (int n = blockIdx.x * 256 + threadIdx.x; n < N_NODES;
         n += gridDim.x * 256)
        m = fmaxf(m, gate[n]);
    __shared__ float red[256];
    red[threadIdx.x] = m;
    __syncthreads();
    for (int s = 128; s > 0; s >>= 1) {
        if (threadIdx.x < s)
            red[threadIdx.x] = fmaxf(red[threadIdx.x], red[threadIdx.x + s]);
        __syncthreads();
    }
    if (threadIdx.x == 0) atomicMax(gmax, fkey(red[0]));
}

// -------- exp(gate - max), block-reduced sum --------
__global__ __launch_bounds__(256) void egate_kernel(
        float* __restrict__ gate, const unsigned* __restrict__ gmax,
        float* __restrict__ gsum) {
    const int n = blockIdx.x * 256 + threadIdx.x;
    float e = 0.f;
    if (n < N_NODES) {
        float m = funkey(*gmax);
        e = expf(gate[n] - m);
        gate[n] = e;
    }
    __shared__ float red[256];
    red[threadIdx.x] = e;
    __syncthreads();
    for (int s = 128; s > 0; s >>= 1) {
        if (threadIdx.x < s) red[threadIdx.x] += red[threadIdx.x + s];
        __syncthreads();
    }
    if (threadIdx.x == 0) atomicAdd(gsum, red[0]);
}

// -------- weighted pooling --------
__global__ __launch_bounds__(256) void final_kernel(
        const float* __restrict__ x2, const float* __restrict__ egate,
        const float* __restrict__ gsum, float* __restrict__ out) {
    const int c   = threadIdx.x & 63;
    const int sub = threadIdx.x >> 6;
    float acc = 0.f;
    for (int n = blockIdx.x * 4 + sub; n < N_NODES; n += gridDim.x * 4)
        acc += egate[n] * x2[(size_t)n * HID + c];
    __shared__ float red[256];
    red[threadIdx.x] = acc;
    __syncthreads();
    if (threadIdx.x < 64) {
        float t = red[threadIdx.x] + red[64 + threadIdx.x] +
                  red[128 + threadIdx.x] + red[192 + threadIdx.x];
        atomicAdd(&out[c], t / (*gsum));
    }
}

extern "C" void kernel_launch(void* const* d_in, const int* in_sizes, int n_in,
                              void* d_out, int out_size, void* d_ws, size_t ws_size,
                              hipStream_t stream) {
    const float* node_feats = (const float*)d_in[0];
    const int*   ei         = (const int*)d_in[1];
    const float* W1   = (const float*)d_in[2];
    const float* as1  = (const float*)d_in[3];
    const float* ad1  = (const float*)d_in[4];
    const float* b1   = (const float*)d_in[5];
    const float* W2   = (const float*)d_in[6];
    const float* as2  = (const float*)d_in[7];
    const float* ad2  = (const float*)d_in[8];
    const float* b2   = (const float*)d_in[9];
    const float* gW1  = (const float*)d_in[10];
    const float* gb1  = (const float*)d_in[11];
    const float* gW2  = (const float*)d_in[12];
    const float* gb2  = (const float*)d_in[13];
    float* out = (float*)d_out;

    // ---- workspace layout (4-byte units) ----
    float* f = (float*)d_ws;
    size_t o = 0;
    float* x2   = f + o; o += (size_t)N_NODES * HID;     // f32
    float* als1 = f + o; o += (size_t)N_NODES * HEADS;
    float* ald1 = f + o; o += (size_t)N_NODES * HEADS;
    float* als2 = f + o; o += N_NODES;
    float* ald2 = f + o; o += N_NODES;
    float* gate = f + o; o += N_NODES;
    int* csr    = (int*)(f + o); o += E_TOT;
    int* rowptr = (int*)(f + o); o += N_NODES;
    u16* h1b    = (u16*)(f + o); o += (size_t)N_NODES * C1 / 2;   // bf16
    u16* x1b    = (u16*)(f + o); o += (size_t)N_NODES * C1 / 2;   // bf16
    u16* h2b    = (u16*)(f + o); o += (size_t)N_NODES * HID / 2;  // bf16
    u16* W1t    = (u16*)(f + o); o += (size_t)EMB * C1 / 2;
    u16* W2t    = (u16*)(f + o); o += (size_t)C1 * HID / 2;
    // ---- contiguous zero region ----
    float* zero0 = f + o;
    int* deg    = (int*)(f + o); o += N_NODES;
    int* cursor = (int*)(f + o); o += N_NODES;
    float* scal = f + o; o += 2;  // [0]=gmax key (uint), [1]=gsum
    size_t zbytes = (size_t)((f + o) - zero0) * sizeof(float);

    hipMemsetAsync(zero0, 0, zbytes, stream);
    hipMemsetAsync(out, 0, (size_t)out_size * sizeof(float), stream);

    const int EB = (E_TOT + 255) / 256;            // 3321
    const int GB = (N_NODES + 63) / 64;            // 782

    // ----- CSR build + weight convert -----
    conv_w_kernel<<<(EMB * C1 + 255) / 256, 256, 0, stream>>>(W1, W2, W1t, W2t);
    deg_kernel<<<EB, 256, 0, stream>>>(ei, deg);
    scan_kernel<<<1, 1024, 0, stream>>>(deg, rowptr);
    fill_kernel<<<EB, 256, 0, stream>>>(ei, rowptr, cursor, csr);

    // ----- layer 1 -----
    gemm1_mfma<<<GB, 256, 0, stream>>>(node_feats, W1t, h1b);
    al1_kernel<<<N_NODES, 256, 0, stream>>>(h1b, as1, ad1, als1, ald1);
    agg1_kernel<<<N_NODES, 256, 0, stream>>>(csr, rowptr, deg, h1b, als1, ald1,
                                             b1, x1b);

    // ----- layer 2 -----
    gemm2_mfma<<<GB, 256, 0, stream>>>(x1b, W2t, h2b);
    al2_kernel<<<N_NODES / 4, 256, 0, stream>>>(h2b, as2, ad2, als2, ald2);
    agg2_kernel<<<N_NODES, 256, 0, stream>>>(csr, rowptr, deg, h2b, als2, ald2,
                                             b2, x2);

    // ----- attentional pooling -----
    gate_kernel<<<N_NODES / 4, 256, 0, stream>>>(x2, gW1, gb1, gW2, gb2, gate);
    gmax_kernel<<<48, 256, 0, stream>>>(gate, (unsigned*)&scal[0]);
    egate_kernel<<<(N_NODES + 255) / 256, 256, 0, stream>>>(
        gate, (const unsigned*)&scal[0], &scal[1]);
    final_kernel<<<256, 256, 0, stream>>>(x2, gate, &scal[1], out);
}